// Round 2
// baseline (3068.488 us; speedup 1.0000x reference)
//
#include <hip/hip_runtime.h>
#include <hip/hip_bf16.h>

typedef __hip_bfloat16 bf16;

// ---------------------------------------------------------------------------
// Dtype detector: inputs may be stored bf16 OR fp32 (element counts match
// either way). Read first 4096 even 16-bit halves of x_t: true-bf16 data has
// sane exponents; fp32 low-halves are random bits -> ~84% absurd exponents.
// flag = 1 -> fp32 storage, 0 -> bf16 storage.
// ---------------------------------------------------------------------------
__global__ void detect_k(const unsigned short* __restrict__ p, int* __restrict__ flag)
{
    __shared__ int cnt;
    if (threadIdx.x == 0) cnt = 0;
    __syncthreads();
    int bad = 0;
    for (int i = threadIdx.x; i < 4096; i += 256) {
        unsigned short u = p[2 * i];
        int e = (u >> 7) & 0xFF;
        if (e != 0 && (e < 100 || e > 140)) bad++;
    }
    atomicAdd(&cnt, bad);
    __syncthreads();
    if (threadIdx.x == 0) *flag = (cnt > 1024) ? 1 : 0;
}

// ingest: convert one input array to fp32 per detected storage dtype
__global__ void ingest_k(const void* __restrict__ src, float* __restrict__ dst,
                         long n, const int* __restrict__ flag)
{
    long i = (long)blockIdx.x * 256 + threadIdx.x;
    if (i >= n) return;
    if (*flag) dst[i] = ((const float*)src)[i];
    else       dst[i] = __bfloat162float(((const bf16*)src)[i]);
}

// ---------------------------------------------------------------------------
// Generic batched fp32 GEMM: C[b](MxN) (+)= A_eff[b](MxK) @ B_eff[b](KxN) (+bias)
// A_eff[m][k] = TRA ? A[k*lda+m] : A[m*lda+k];  B_eff[k][n] = TRB ? B[n*ldb+k] : B[k*ldb+n]
// 64x64 tile, BK=16, 256 threads, 4x4 micro-tile.
// ---------------------------------------------------------------------------
template <bool TRA, bool TRB, bool ACCUM, bool BIAS>
__launch_bounds__(256)
__global__ void gemm_k(const float* __restrict__ A, int lda, long sA,
                       const float* __restrict__ Bm, int ldb, long sB,
                       float* __restrict__ C, int ldc, long sC,
                       const float* __restrict__ bias,
                       int M, int N, int K)
{
    __shared__ float As[16][64];
    __shared__ float Bs[16][64];
    const int bz = blockIdx.z;
    const float* Ab = A + (long)bz * sA;
    const float* Bb = Bm + (long)bz * sB;
    float* Cb = C + (long)bz * sC;
    const int m0 = blockIdx.y * 64, n0 = blockIdx.x * 64;
    const int tid = threadIdx.x;
    const int tm = tid >> 4, tn = tid & 15;

    float acc[4][4];
#pragma unroll
    for (int i = 0; i < 4; i++)
#pragma unroll
        for (int j = 0; j < 4; j++) acc[i][j] = 0.f;

    for (int k0 = 0; k0 < K; k0 += 16) {
        if (TRA) {
#pragma unroll
            for (int i = 0; i < 4; i++) {
                int idx = tid + i * 256;
                int kk = idx >> 6, mm = idx & 63;
                float v = 0.f;
                if (m0 + mm < M && k0 + kk < K)
                    v = Ab[(long)(k0 + kk) * lda + (m0 + mm)];
                As[kk][mm] = v;
            }
        } else {
#pragma unroll
            for (int i = 0; i < 4; i++) {
                int idx = tid + i * 256;
                int mm = idx >> 4, kk = idx & 15;
                float v = 0.f;
                if (m0 + mm < M && k0 + kk < K)
                    v = Ab[(long)(m0 + mm) * lda + (k0 + kk)];
                As[kk][mm] = v;
            }
        }
        if (TRB) {
#pragma unroll
            for (int i = 0; i < 4; i++) {
                int idx = tid + i * 256;
                int nn = idx >> 4, kk = idx & 15;
                float v = 0.f;
                if (n0 + nn < N && k0 + kk < K)
                    v = Bb[(long)(n0 + nn) * ldb + (k0 + kk)];
                Bs[kk][nn] = v;
            }
        } else {
#pragma unroll
            for (int i = 0; i < 4; i++) {
                int idx = tid + i * 256;
                int kk = idx >> 6, nn = idx & 63;
                float v = 0.f;
                if (n0 + nn < N && k0 + kk < K)
                    v = Bb[(long)(k0 + kk) * ldb + (n0 + nn)];
                Bs[kk][nn] = v;
            }
        }
        __syncthreads();
#pragma unroll
        for (int kk = 0; kk < 16; kk++) {
            float a[4], bv[4];
#pragma unroll
            for (int i = 0; i < 4; i++) a[i] = As[kk][tm * 4 + i];
#pragma unroll
            for (int j = 0; j < 4; j++) bv[j] = Bs[kk][tn * 4 + j];
#pragma unroll
            for (int i = 0; i < 4; i++)
#pragma unroll
                for (int j = 0; j < 4; j++)
                    acc[i][j] = fmaf(a[i], bv[j], acc[i][j]);
        }
        __syncthreads();
    }

#pragma unroll
    for (int i = 0; i < 4; i++) {
        int m = m0 + tm * 4 + i;
        if (m >= M) continue;
        float bv = BIAS ? bias[m] : 0.f;
#pragma unroll
        for (int j = 0; j < 4; j++) {
            int n = n0 + tn * 4 + j;
            if (n >= N) continue;
            long off = (long)m * ldc + n;
            float r = acc[i][j] + bv;
            if (ACCUM) r += Cb[off];
            Cb[off] = r;
        }
    }
}

// Softmax over batch axis (16) of att[b][idx]
__global__ void softmax_b_k(float* __restrict__ att, long NN)
{
    long idx = (long)blockIdx.x * 256 + threadIdx.x;
    if (idx >= NN) return;
    float r[16];
    float mx = -1e30f;
#pragma unroll
    for (int b = 0; b < 16; b++) {
        r[b] = att[(long)b * NN + idx];
        mx = fmaxf(mx, r[b]);
    }
    float s = 0.f;
#pragma unroll
    for (int b = 0; b < 16; b++) { r[b] = expf(r[b] - mx); s += r[b]; }
    float inv = 1.f / s;
#pragma unroll
    for (int b = 0; b < 16; b++) att[(long)b * NN + idx] = r[b] * inv;
}

// M[b][c][d] = softmax_c(gram_t)[b][c][d] + softmax_c(gram_s)[b][c][d]
__global__ void gram_sm_k(const float* __restrict__ gt, const float* __restrict__ gs,
                          float* __restrict__ Mo)
{
    int b = blockIdx.x;
    int d = blockIdx.y * 64 + threadIdx.x;
    const float* gtb = gt + (long)b * 65536;
    const float* gsb = gs + (long)b * 65536;
    float* mb = Mo + (long)b * 65536;
    float mt = -1e30f, ms = -1e30f;
    for (int c = 0; c < 256; c++) {
        mt = fmaxf(mt, gtb[c * 256 + d]);
        ms = fmaxf(ms, gsb[c * 256 + d]);
    }
    float st = 0.f, ss = 0.f;
    for (int c = 0; c < 256; c++) {
        st += expf(gtb[c * 256 + d] - mt);
        ss += expf(gsb[c * 256 + d] - ms);
    }
    float it = 1.f / st, is = 1.f / ss;
    for (int c = 0; c < 256; c++)
        mb[c * 256 + d] = expf(gtb[c * 256 + d] - mt) * it +
                          expf(gsb[c * 256 + d] - ms) * is;
}

// final cast: d_out = concat(out_t, out_s) in detected output dtype
__global__ void cast_out_k(const float* __restrict__ t, const float* __restrict__ s,
                           void* __restrict__ out, long nt, long ntot,
                           const int* __restrict__ flag)
{
    long idx = (long)blockIdx.x * 256 + threadIdx.x;
    if (idx >= ntot) return;
    float v = (idx < nt) ? t[idx] : s[idx - nt];
    if (*flag) ((float*)out)[idx] = v;
    else       ((bf16*)out)[idx] = __float2bfloat16(v);
}

// ---------------------------------------------------------------------------
// Direct 3x3 conv (SAME), 27 output channels, fp32 in/weights.
// grid (H, B), block 256. LDS stages 64-channel x 3-row strip with halo.
// ---------------------------------------------------------------------------
__global__ void conv3x3_k(const float* __restrict__ X, const float* __restrict__ Wc,
                          const float* __restrict__ bias, float* __restrict__ Y,
                          int H, int W)
{
    const int h = blockIdx.x, b = blockIdx.y;
    const int tid = threadIdx.x;
    const int N = H * W;
    const int Wp = W + 2;
    extern __shared__ float tile[];  // [64][3][W+2]
    const float* Xb = X + (long)b * 256 * N;
    const int npair = 27 * W;
    float acc[4] = {0.f, 0.f, 0.f, 0.f};

    for (int c0 = 0; c0 < 256; c0 += 64) {
        __syncthreads();
        for (int e = tid; e < 64 * 3; e += 256) {
            int c = e / 3, r = e % 3;
            tile[(c * 3 + r) * Wp + 0] = 0.f;
            tile[(c * 3 + r) * Wp + W + 1] = 0.f;
        }
        for (int e = tid; e < 64 * 3 * W; e += 256) {
            int c = e / (3 * W);
            int rem = e % (3 * W);
            int r = rem / W, w = rem % W;
            int hh = h + r - 1;
            float v = 0.f;
            if (hh >= 0 && hh < H) v = Xb[(long)(c0 + c) * N + hh * W + w];
            tile[(c * 3 + r) * Wp + w + 1] = v;
        }
        __syncthreads();
        int ai = 0;
        for (int pi = tid; pi < npair; pi += 256, ai++) {
            int o = pi / W, w = pi % W;
            float s = acc[ai];
            for (int c = 0; c < 64; c++) {
                const float* wp = Wc + ((long)o * 256 + c0 + c) * 9;
                const float* tp = tile + (c * 3) * Wp + w;
                s = fmaf(tp[0],          wp[0], s);
                s = fmaf(tp[1],          wp[1], s);
                s = fmaf(tp[2],          wp[2], s);
                s = fmaf(tp[Wp + 0],     wp[3], s);
                s = fmaf(tp[Wp + 1],     wp[4], s);
                s = fmaf(tp[Wp + 2],     wp[5], s);
                s = fmaf(tp[2 * Wp + 0], wp[6], s);
                s = fmaf(tp[2 * Wp + 1], wp[7], s);
                s = fmaf(tp[2 * Wp + 2], wp[8], s);
            }
            acc[ai] = s;
        }
    }
    int ai = 0;
    for (int pi = tid; pi < npair; pi += 256, ai++) {
        int o = pi / W, w = pi % W;
        Y[((long)b * 27 + o) * N + h * W + w] = acc[ai] + bias[o];
    }
}

// ---------------------------------------------------------------------------
// Bilinear sampler for DCN tap k: S[b][c][p] = mask * bilinear(X, p, tap k)
// grid (N/64, B), block 256.
// ---------------------------------------------------------------------------
__global__ void sample_k(const float* __restrict__ X, const float* __restrict__ OO,
                         float* __restrict__ S, int H, int W, int ktap)
{
    const int b = blockIdx.y;
    const int p0 = blockIdx.x * 64;
    const int tid = threadIdx.x;
    const int N = H * W;
    __shared__ float wgt[64][4];
    __shared__ int adr[64][4];
    if (tid < 64) {
        int p = p0 + tid;
        int h = p / W, w = p % W;
        const float* oob = OO + (long)b * 27 * N;
        float oy = oob[(2 * ktap) * N + p];
        float ox = oob[(2 * ktap + 1) * N + p];
        float mz = oob[(18 + ktap) * N + p];
        float mask = 1.f / (1.f + expf(-mz));
        float y = (float)(h - 1 + ktap / 3) + oy;
        float x = (float)(w - 1 + ktap % 3) + ox;
        float y0 = floorf(y), x0 = floorf(x);
        float wy = y - y0, wx = x - x0;
        float ys[2] = {y0, y0 + 1.f};
        float xs[2] = {x0, x0 + 1.f};
        float wys[2] = {1.f - wy, wy};
        float wxs[2] = {1.f - wx, wx};
#pragma unroll
        for (int iy = 0; iy < 2; iy++)
#pragma unroll
            for (int ix = 0; ix < 2; ix++) {
                float yy = ys[iy], xx = xs[ix];
                bool valid = (yy >= 0.f) && (yy <= (float)(H - 1)) &&
                             (xx >= 0.f) && (xx <= (float)(W - 1));
                float wv = valid ? wys[iy] * wxs[ix] * mask : 0.f;
                int yc = (int)fminf(fmaxf(yy, 0.f), (float)(H - 1));
                int xc = (int)fminf(fmaxf(xx, 0.f), (float)(W - 1));
                wgt[tid][iy * 2 + ix] = wv;
                adr[tid][iy * 2 + ix] = yc * W + xc;
            }
    }
    __syncthreads();
    int pl = tid & 63, cw = tid >> 6;
    float w0 = wgt[pl][0], w1 = wgt[pl][1], w2 = wgt[pl][2], w3 = wgt[pl][3];
    int a0 = adr[pl][0], a1 = adr[pl][1], a2 = adr[pl][2], a3 = adr[pl][3];
    const float* Xb = X + (long)b * 256 * N;
    float* Sb = S + (long)b * 256 * N;
    int p = p0 + pl;
    for (int c = cw; c < 256; c += 4) {
        const float* pc = Xb + (long)c * N;
        float v = w0 * pc[a0] + w1 * pc[a1] + w2 * pc[a2] + w3 * pc[a3];
        Sb[(long)c * N + p] = v;
    }
}

// Wk[k][o][c] = w[(o*256+c)*9 + k]  (fp32 source)
__global__ void wkprep_k(const float* __restrict__ w, float* __restrict__ Wk)
{
    long idx = (long)blockIdx.x * 256 + threadIdx.x;
    if (idx >= 9L * 65536) return;
    int k = (int)(idx / 65536);
    int oc = (int)(idx % 65536);
    Wk[idx] = w[(long)oc * 9 + k];
}

// ---------------------------------------------------------------------------
extern "C" void kernel_launch(void* const* d_in, const int* in_sizes, int n_in,
                              void* d_out, int out_size, void* d_ws, size_t ws_size,
                              hipStream_t stream)
{
    const int B = 16, C = 256;
    const int Nt = 256, Ns = 1024;  // 16x16, 32x32
    const long sXt = (long)C * Nt, sXs = (long)C * Ns;
    dim3 blk(256);

    float* ws = (float*)d_ws;
    int* flag = (int*)d_ws;         // first 16 floats reserved for flag
    long off = 16;
    auto alloc = [&](long n) { float* p = ws + off; off += n; return p; };

    float* xt32     = alloc((long)B * C * Nt);   // 1,048,576
    float* xs32     = alloc((long)B * C * Ns);   // 4,194,304  (-> out_s_f32)
    float* Wf       = alloc(1469440);            // all weights fp32
    float* q_t      = alloc((long)B * 32 * Nt);
    float* k_t      = alloc((long)B * 32 * Nt);
    float* v_t      = alloc((long)B * C * Nt);   // -> S_t
    float* q_s      = alloc((long)B * 32 * Ns);
    float* k_s      = alloc((long)B * 32 * Ns);
    float* v_s      = alloc((long)B * C * Ns);
    float* gram_t   = alloc((long)B * C * C);    // -> out_t_f32
    float* gram_s   = alloc((long)B * C * C);    // -> Wk_t
    float* Mc       = alloc((long)B * C * C);    // -> Wk_s
    float* att_t    = alloc((long)B * Nt * Nt);
    float* att_slab = alloc((long)B * Ns * 256); // -> S_s
    float* at       = alloc((long)B * C * Nt);
    float* asr      = alloc((long)B * C * Ns);
    float* oo_t     = alloc((long)B * 27 * Nt);
    float* oo_s     = alloc((long)B * 27 * Ns);

    // aliases (lifetimes disjoint, verified against launch order)
    float* out_t_f32 = gram_t;
    float* out_s_f32 = xs32;
    float* S_t       = v_t;
    float* S_s       = att_slab;
    float* Wk_t      = gram_s;
    float* Wk_s      = Mc;

    // ---- 0) detect storage dtype ----
    detect_k<<<dim3(1), blk, 0, stream>>>((const unsigned short*)d_in[0], flag);

    // ---- 1) ingest inputs to fp32 ----
    auto ingest = [&](const void* src, float* dst, long n) {
        ingest_k<<<dim3((unsigned)((n + 255) / 256)), blk, 0, stream>>>(src, dst, n, flag);
    };
    ingest(d_in[0], xt32, (long)B * C * Nt);
    ingest(d_in[0], at,   (long)B * C * Nt);   // at starts as x_t
    ingest(d_in[1], xs32, (long)B * C * Ns);
    ingest(d_in[1], asr,  (long)B * C * Ns);   // asr starts as x_s
    long woff[22]; long acc = 0;
    for (int i = 2; i < 22; i++) { woff[i] = acc; acc += in_sizes[i]; }
    for (int i = 2; i < 22; i++) ingest(d_in[i], Wf + woff[i], in_sizes[i]);
    const float *tq_w = Wf + woff[2],  *tq_b = Wf + woff[3];
    const float *tk_w = Wf + woff[4],  *tk_b = Wf + woff[5];
    const float *tv_w = Wf + woff[6],  *tv_b = Wf + woff[7];
    const float *sq_w = Wf + woff[8],  *sq_b = Wf + woff[9];
    const float *sk_w = Wf + woff[10], *sk_b = Wf + woff[11];
    const float *sv_w = Wf + woff[12], *sv_b = Wf + woff[13];
    const float *t_off_w = Wf + woff[14], *t_off_b = Wf + woff[15];
    const float *t_dcn_w = Wf + woff[16], *t_dcn_b = Wf + woff[17];
    const float *s_off_w = Wf + woff[18], *s_off_b = Wf + woff[19];
    const float *s_dcn_w = Wf + woff[20], *s_dcn_b = Wf + woff[21];

    // ---- 2) q,k,v projections ----
    gemm_k<false, false, false, true><<<dim3(Nt / 64, 1, B), blk, 0, stream>>>(
        tq_w, 256, 0, xt32, Nt, sXt, q_t, Nt, (long)32 * Nt, tq_b, 32, Nt, 256);
    gemm_k<false, false, false, true><<<dim3(Nt / 64, 1, B), blk, 0, stream>>>(
        tk_w, 256, 0, xt32, Nt, sXt, k_t, Nt, (long)32 * Nt, tk_b, 32, Nt, 256);
    gemm_k<false, false, false, true><<<dim3(Nt / 64, 4, B), blk, 0, stream>>>(
        tv_w, 256, 0, xt32, Nt, sXt, v_t, Nt, sXt, tv_b, 256, Nt, 256);
    gemm_k<false, false, false, true><<<dim3(Ns / 64, 1, B), blk, 0, stream>>>(
        sq_w, 256, 0, xs32, Ns, sXs, q_s, Ns, (long)32 * Ns, sq_b, 32, Ns, 256);
    gemm_k<false, false, false, true><<<dim3(Ns / 64, 1, B), blk, 0, stream>>>(
        sk_w, 256, 0, xs32, Ns, sXs, k_s, Ns, (long)32 * Ns, sk_b, 32, Ns, 256);
    gemm_k<false, false, false, true><<<dim3(Ns / 64, 4, B), blk, 0, stream>>>(
        sv_w, 256, 0, xs32, Ns, sXs, v_s, Ns, sXs, sv_b, 256, Ns, 256);

    // ---- 3) gram matrices: G[b] = f[b] @ f[b]^T ----
    gemm_k<false, true, false, false><<<dim3(4, 4, B), blk, 0, stream>>>(
        xt32, Nt, sXt, xt32, Nt, sXt, gram_t, 256, (long)C * C, nullptr, 256, 256, Nt);
    gemm_k<false, true, false, false><<<dim3(4, 4, B), blk, 0, stream>>>(
        xs32, Ns, sXs, xs32, Ns, sXs, gram_s, 256, (long)C * C, nullptr, 256, 256, Ns);

    // ---- 4) M = softmax_c(gram_t) + softmax_c(gram_s) ----
    gram_sm_k<<<dim3(B, 4), dim3(64), 0, stream>>>(gram_t, gram_s, Mc);

    // ---- 5) channel attention (self+cross combined): at += M@x_t; asr += M@x_s
    gemm_k<false, false, true, false><<<dim3(Nt / 64, 4, B), blk, 0, stream>>>(
        Mc, 256, (long)C * C, xt32, Nt, sXt, at, Nt, sXt, nullptr, 256, Nt, 256);
    gemm_k<false, false, true, false><<<dim3(Ns / 64, 4, B), blk, 0, stream>>>(
        Mc, 256, (long)C * C, xs32, Ns, sXs, asr, Ns, sXs, nullptr, 256, Ns, 256);

    // ---- 6) template spatial attention ----
    gemm_k<true, false, false, false><<<dim3(4, 4, B), blk, 0, stream>>>(
        q_t, Nt, (long)32 * Nt, k_t, Nt, (long)32 * Nt, att_t, Nt, (long)Nt * Nt,
        nullptr, Nt, Nt, 32);
    softmax_b_k<<<dim3((Nt * Nt) / 256), blk, 0, stream>>>(att_t, (long)Nt * Nt);
    gemm_k<false, false, true, false><<<dim3(Nt / 64, 4, B), blk, 0, stream>>>(
        v_t, Nt, sXt, att_t, Nt, (long)Nt * Nt, at, Nt, sXt, nullptr, 256, Nt, Nt);

    // ---- 7) search spatial attention, processed in 4 m-slabs of 256 ----
    for (int m0 = 0; m0 < Ns; m0 += 256) {
        gemm_k<true, false, false, false><<<dim3(4, 16, B), blk, 0, stream>>>(
            q_s, Ns, (long)32 * Ns, k_s + m0, Ns, (long)32 * Ns,
            att_slab, 256, (long)Ns * 256, nullptr, Ns, 256, 32);
        softmax_b_k<<<dim3((Ns * 256) / 256), blk, 0, stream>>>(att_slab, (long)Ns * 256);
        gemm_k<false, false, true, false><<<dim3(4, 4, B), blk, 0, stream>>>(
            v_s, Ns, sXs, att_slab, 256, (long)Ns * 256,
            asr + m0, Ns, sXs, nullptr, 256, 256, Ns);
    }

    // ---- 8) offset convs (3x3, 27 out channels) ----
    conv3x3_k<<<dim3(16, B), blk, 64 * 3 * 18 * sizeof(float), stream>>>(
        at, t_off_w, t_off_b, oo_t, 16, 16);
    conv3x3_k<<<dim3(32, B), blk, 64 * 3 * 34 * sizeof(float), stream>>>(
        asr, s_off_w, s_off_b, oo_s, 32, 32);

    // ---- 9) reorder DCN weights: Wk[k][o][c] ----
    wkprep_k<<<dim3(2304), blk, 0, stream>>>(t_dcn_w, Wk_t);
    wkprep_k<<<dim3(2304), blk, 0, stream>>>(s_dcn_w, Wk_s);

    // ---- 10) deformable conv: out = bias + sum_k Wk @ S_k ----
    for (int k = 0; k < 9; k++) {
        sample_k<<<dim3(Nt / 64, B), blk, 0, stream>>>(at, oo_t, S_t, 16, 16, k);
        if (k == 0)
            gemm_k<false, false, false, true><<<dim3(Nt / 64, 4, B), blk, 0, stream>>>(
                Wk_t + (long)k * 65536, 256, 0, S_t, Nt, sXt, out_t_f32, Nt, sXt,
                t_dcn_b, 256, Nt, 256);
        else
            gemm_k<false, false, true, false><<<dim3(Nt / 64, 4, B), blk, 0, stream>>>(
                Wk_t + (long)k * 65536, 256, 0, S_t, Nt, sXt, out_t_f32, Nt, sXt,
                nullptr, 256, Nt, 256);

        sample_k<<<dim3(Ns / 64, B), blk, 0, stream>>>(asr, oo_s, S_s, 32, 32, k);
        if (k == 0)
            gemm_k<false, false, false, true><<<dim3(Ns / 64, 4, B), blk, 0, stream>>>(
                Wk_s + (long)k * 65536, 256, 0, S_s, Ns, sXs, out_s_f32, Ns, sXs,
                s_dcn_b, 256, Ns, 256);
        else
            gemm_k<false, false, true, false><<<dim3(Ns / 64, 4, B), blk, 0, stream>>>(
                Wk_s + (long)k * 65536, 256, 0, S_s, Ns, sXs, out_s_f32, Ns, sXs,
                nullptr, 256, Ns, 256);
    }

    // ---- 11) emit output (out_t then out_s, concatenated) ----
    long nt = (long)B * C * Nt;
    long ntot = nt + (long)B * C * Ns;
    cast_out_k<<<dim3((unsigned)((ntot + 255) / 256)), blk, 0, stream>>>(
        out_t_f32, out_s_f32, d_out, nt, ntot, flag);
}

// Round 5
// 1827.748 us; speedup vs baseline: 1.6788x; 1.6788x over previous
//
#include <hip/hip_runtime.h>
#include <hip/hip_bf16.h>

typedef __hip_bfloat16 bf16;
typedef __attribute__((ext_vector_type(8))) short short8;
typedef __attribute__((ext_vector_type(4))) float f32x4;

__device__ __forceinline__ short f2b(float v)
{
    union { bf16 b; short s; } u;
    u.b = __float2bfloat16(v);
    return u.s;
}
__device__ __forceinline__ float b2f(short s)
{
    union { short s; bf16 b; } u;
    u.s = s;
    return __bfloat162float(u.b);
}
// split fp32 -> (hi, lo) bf16 pair; hi+lo carries ~16 mantissa bits
__device__ __forceinline__ void splt(float v, short& hi, short& lo)
{
    hi = f2b(v);
    lo = f2b(v - b2f(hi));
}

// ---------------------------------------------------------------------------
// Dtype detector (validated round 2): flag=1 -> fp32 storage, 0 -> bf16.
// ---------------------------------------------------------------------------
__global__ void detect_k(const unsigned short* __restrict__ p, int* __restrict__ flag)
{
    __shared__ int cnt;
    if (threadIdx.x == 0) cnt = 0;
    __syncthreads();
    int bad = 0;
    for (int i = threadIdx.x; i < 4096; i += 256) {
        unsigned short u = p[2 * i];
        int e = (u >> 7) & 0xFF;
        if (e != 0 && (e < 100 || e > 140)) bad++;
    }
    atomicAdd(&cnt, bad);
    __syncthreads();
    if (threadIdx.x == 0) *flag = (cnt > 1024) ? 1 : 0;
}

// ---------------------------------------------------------------------------
// Fused ingest: all inputs -> fp32 workspace in ONE launch. 24 segments.
// ---------------------------------------------------------------------------
#define NSEG 24
struct IArgs {
    const void* src[NSEG];
    float* dst[NSEG];
    long start[NSEG + 1];
};

__global__ void ingest_all_k(IArgs a, const int* __restrict__ flag)
{
    long i = (long)blockIdx.x * 256 + threadIdx.x;
    if (i >= a.start[NSEG]) return;
    int s = 0;
#pragma unroll
    for (int j = 1; j < NSEG; j++) s += (i >= a.start[j]) ? 1 : 0;
    long idx = i - a.start[s];
    float v;
    if (*flag) v = ((const float*)a.src[s])[idx];
    else       v = __bfloat162float(((const bf16*)a.src[s])[idx]);
    a.dst[s][idx] = v;
}

// ---------------------------------------------------------------------------
// MFMA bf16 GEMM.  C[b](MxN) (+)= A_eff[b](MxK) @ B_eff[b](KxN) (+bias[m])
// A_eff[m][k] = TRA ? A[k*lda+m] : A[m*lda + k*ksA]          (fp32 source)
// B modes:
//   0: B_eff[k][n] = B[k*ldb + n]                            (fp32)
//   1: B_eff[k][n] = B[n*ldb + k]   (TRB)                    (fp32)
//   3: im2col: k=(c,tap): B_eff[k][n] = X[c*ldb + shifted(n)] (fp32, 3x3 SAME)
//   4: tap9:   k=(c,tap): B_eff[k][n] = S9[(tap*256+c)*ldb+n] (bf16 source)
// PREC=1: plain bf16 (1 MFMA per quadrant-k).  PREC=2: split hi/lo bf16,
// acc += Ahi*Bhi + Ahi*Blo + Alo*Bhi  (~16 mantissa bits, rel ~2e-5).
// Tile 64x64, BK=32, 256 threads = 4 waves, each wave a 32x32 quadrant.
// Requires: K % 32 == 0, N % 64 == 0.  M guarded.
// ---------------------------------------------------------------------------
template <bool TRA, int BMODE, bool ACCUM, bool BIAS, int PREC>
__launch_bounds__(256)
__global__ void mgemm(const float* __restrict__ A, int lda, int ksA, long sA,
                      const void* __restrict__ Bsrc, int ldb, long sB,
                      float* __restrict__ C, int ldc, long sC,
                      const float* __restrict__ bias,
                      int M, int N, int K, int H, int wsh)
{
    __shared__ short As[PREC * 2560];  // [part][64][40]
    __shared__ short Bs[PREC * 2560];

    const int bz = blockIdx.z;
    const float* Ab = A + (long)bz * sA;
    float* Cb = C + (long)bz * sC;
    const int m0 = blockIdx.y * 64, n0 = blockIdx.x * 64;
    const int tid = threadIdx.x;

    f32x4 acc[2][2];
#pragma unroll
    for (int i = 0; i < 2; i++)
#pragma unroll
        for (int j = 0; j < 2; j++) acc[i][j] = (f32x4){0.f, 0.f, 0.f, 0.f};

    const int lane = tid & 63, wv = tid >> 6;
    const int moff = (wv & 1) * 32, noff = (wv >> 1) * 32;
    const int lr = lane & 15, lq = lane >> 4;

    for (int k0 = 0; k0 < K; k0 += 32) {
        // ---- stage A ----
        if (!TRA) {
            int mm = tid >> 2, kk0 = (tid & 3) * 8;
            float vv[8];
            if (m0 + mm < M) {
                if (ksA == 1) {
                    const float4* s4 = (const float4*)(Ab + (long)(m0 + mm) * lda + k0 + kk0);
                    float4 v0 = s4[0], v1 = s4[1];
                    vv[0] = v0.x; vv[1] = v0.y; vv[2] = v0.z; vv[3] = v0.w;
                    vv[4] = v1.x; vv[5] = v1.y; vv[6] = v1.z; vv[7] = v1.w;
                } else {
                    const float* s = Ab + (long)(m0 + mm) * lda + (long)(k0 + kk0) * ksA;
#pragma unroll
                    for (int j = 0; j < 8; j++) vv[j] = s[(long)j * ksA];
                }
            } else {
#pragma unroll
                for (int j = 0; j < 8; j++) vv[j] = 0.f;
            }
            short8 hi, lo;
#pragma unroll
            for (int j = 0; j < 8; j++) {
                short h, l; splt(vv[j], h, l); hi[j] = h; lo[j] = l;
            }
            *(short8*)&As[mm * 40 + kk0] = hi;
            if (PREC == 2) *(short8*)&As[2560 + mm * 40 + kk0] = lo;
        } else {
            int kk = tid >> 3, mm0 = (tid & 7) * 8;
            const float4* s4 = (const float4*)(Ab + (long)(k0 + kk) * lda + m0 + mm0);
            float4 v0 = s4[0], v1 = s4[1];
            float vv[8] = {v0.x, v0.y, v0.z, v0.w, v1.x, v1.y, v1.z, v1.w};
#pragma unroll
            for (int j = 0; j < 8; j++) {
                float v = (m0 + mm0 + j < M) ? vv[j] : 0.f;
                short h, l; splt(v, h, l);
                As[(mm0 + j) * 40 + kk] = h;
                if (PREC == 2) As[2560 + (mm0 + j) * 40 + kk] = l;
            }
        }

        // ---- stage B ----
        if (BMODE == 0) {
            int kk = tid >> 3, nn0 = (tid & 7) * 8;
            const float4* s4 = (const float4*)((const float*)Bsrc + (long)bz * sB +
                                               (long)(k0 + kk) * ldb + n0 + nn0);
            float4 v0 = s4[0], v1 = s4[1];
            float vv[8] = {v0.x, v0.y, v0.z, v0.w, v1.x, v1.y, v1.z, v1.w};
#pragma unroll
            for (int j = 0; j < 8; j++) {
                short h, l; splt(vv[j], h, l);
                Bs[(nn0 + j) * 40 + kk] = h;
                if (PREC == 2) Bs[2560 + (nn0 + j) * 40 + kk] = l;
            }
        } else if (BMODE == 1) {
            int nn = tid >> 2, kk0 = (tid & 3) * 8;
            const float4* s4 = (const float4*)((const float*)Bsrc + (long)bz * sB +
                                               (long)(n0 + nn) * ldb + k0 + kk0);
            float4 v0 = s4[0], v1 = s4[1];
            float vv[8] = {v0.x, v0.y, v0.z, v0.w, v1.x, v1.y, v1.z, v1.w};
            short8 hi, lo;
#pragma unroll
            for (int j = 0; j < 8; j++) {
                short h, l; splt(vv[j], h, l); hi[j] = h; lo[j] = l;
            }
            *(short8*)&Bs[nn * 40 + kk0] = hi;
            if (PREC == 2) *(short8*)&Bs[2560 + nn * 40 + kk0] = lo;
        } else if (BMODE == 3) {
            int kk = tid >> 3, nn0 = (tid & 7) * 8;
            int kc = k0 + kk;
            int c = kc / 9, tap = kc - 9 * c;
            int dy = tap / 3 - 1, dx = tap % 3 - 1;
            int W = 1 << wsh;
            const float* base = (const float*)Bsrc + (long)bz * sB + (long)c * ldb;
#pragma unroll
            for (int j = 0; j < 8; j++) {
                int n = n0 + nn0 + j;
                int h = (n >> wsh) + dy, w = (n & (W - 1)) + dx;
                float v = (h >= 0 && h < H && w >= 0 && w < W) ? base[(h << wsh) + w] : 0.f;
                short hh, ll; splt(v, hh, ll);
                Bs[(nn0 + j) * 40 + kk] = hh;
                if (PREC == 2) Bs[2560 + (nn0 + j) * 40 + kk] = ll;
            }
        } else {  // BMODE 4: bf16 per-tap sampled source (PREC=1 use only)
            int kk = tid >> 3, nn0 = (tid & 7) * 8;
            int kc = k0 + kk;
            int c = kc / 9, tap = kc - 9 * c;
            const short* s = (const short*)Bsrc + (long)bz * sB + (long)(tap * 256 + c) * ldb + n0 + nn0;
            short8 v = *(const short8*)s;
#pragma unroll
            for (int j = 0; j < 8; j++) {
                Bs[(nn0 + j) * 40 + kk] = v[j];
                if (PREC == 2) Bs[2560 + (nn0 + j) * 40 + kk] = 0;
            }
        }
        __syncthreads();

        // ---- compute ----
        short8 a0h = *(short8*)&As[(moff + lr) * 40 + lq * 8];
        short8 a1h = *(short8*)&As[(moff + 16 + lr) * 40 + lq * 8];
        short8 b0h = *(short8*)&Bs[(noff + lr) * 40 + lq * 8];
        short8 b1h = *(short8*)&Bs[(noff + 16 + lr) * 40 + lq * 8];
        acc[0][0] = __builtin_amdgcn_mfma_f32_16x16x32_bf16(a0h, b0h, acc[0][0], 0, 0, 0);
        acc[0][1] = __builtin_amdgcn_mfma_f32_16x16x32_bf16(a0h, b1h, acc[0][1], 0, 0, 0);
        acc[1][0] = __builtin_amdgcn_mfma_f32_16x16x32_bf16(a1h, b0h, acc[1][0], 0, 0, 0);
        acc[1][1] = __builtin_amdgcn_mfma_f32_16x16x32_bf16(a1h, b1h, acc[1][1], 0, 0, 0);
        if (PREC == 2) {
            short8 a0l = *(short8*)&As[2560 + (moff + lr) * 40 + lq * 8];
            short8 a1l = *(short8*)&As[2560 + (moff + 16 + lr) * 40 + lq * 8];
            short8 b0l = *(short8*)&Bs[2560 + (noff + lr) * 40 + lq * 8];
            short8 b1l = *(short8*)&Bs[2560 + (noff + 16 + lr) * 40 + lq * 8];
            acc[0][0] = __builtin_amdgcn_mfma_f32_16x16x32_bf16(a0h, b0l, acc[0][0], 0, 0, 0);
            acc[0][1] = __builtin_amdgcn_mfma_f32_16x16x32_bf16(a0h, b1l, acc[0][1], 0, 0, 0);
            acc[1][0] = __builtin_amdgcn_mfma_f32_16x16x32_bf16(a1h, b0l, acc[1][0], 0, 0, 0);
            acc[1][1] = __builtin_amdgcn_mfma_f32_16x16x32_bf16(a1h, b1l, acc[1][1], 0, 0, 0);
            acc[0][0] = __builtin_amdgcn_mfma_f32_16x16x32_bf16(a0l, b0h, acc[0][0], 0, 0, 0);
            acc[0][1] = __builtin_amdgcn_mfma_f32_16x16x32_bf16(a0l, b1h, acc[0][1], 0, 0, 0);
            acc[1][0] = __builtin_amdgcn_mfma_f32_16x16x32_bf16(a1l, b0h, acc[1][0], 0, 0, 0);
            acc[1][1] = __builtin_amdgcn_mfma_f32_16x16x32_bf16(a1l, b1h, acc[1][1], 0, 0, 0);
        }
        __syncthreads();
    }

    // ---- epilogue ----
#pragma unroll
    for (int mi = 0; mi < 2; mi++)
#pragma unroll
        for (int ni = 0; ni < 2; ni++) {
            int col = n0 + noff + ni * 16 + lr;
#pragma unroll
            for (int r = 0; r < 4; r++) {
                int row = m0 + moff + mi * 16 + lq * 4 + r;
                if (row < M) {
                    long o = (long)row * ldc + col;
                    float v = acc[mi][ni][r];
                    if (BIAS) v += bias[row];
                    if (ACCUM) v += Cb[o];
                    Cb[o] = v;
                }
            }
        }
}

// Softmax over batch axis (16) of att[b][idx]
__global__ void softmax_b_k(float* __restrict__ att, long NN)
{
    long idx = (long)blockIdx.x * 256 + threadIdx.x;
    if (idx >= NN) return;
    float r[16];
    float mx = -1e30f;
#pragma unroll
    for (int b = 0; b < 16; b++) {
        r[b] = att[(long)b * NN + idx];
        mx = fmaxf(mx, r[b]);
    }
    float s = 0.f;
#pragma unroll
    for (int b = 0; b < 16; b++) { r[b] = expf(r[b] - mx); s += r[b]; }
    float inv = 1.f / s;
#pragma unroll
    for (int b = 0; b < 16; b++) att[(long)b * NN + idx] = r[b] * inv;
}

// M[b][c][d] = softmax_c(gram_t) + softmax_c(gram_s)
__global__ void gram_sm_k(const float* __restrict__ gt, const float* __restrict__ gs,
                          float* __restrict__ Mo)
{
    int b = blockIdx.x;
    int d = blockIdx.y * 64 + threadIdx.x;
    const float* gtb = gt + (long)b * 65536;
    const float* gsb = gs + (long)b * 65536;
    float* mb = Mo + (long)b * 65536;
    float mt = -1e30f, ms = -1e30f;
    for (int c = 0; c < 256; c++) {
        mt = fmaxf(mt, gtb[c * 256 + d]);
        ms = fmaxf(ms, gsb[c * 256 + d]);
    }
    float st = 0.f, ss = 0.f;
    for (int c = 0; c < 256; c++) {
        st += expf(gtb[c * 256 + d] - mt);
        ss += expf(gsb[c * 256 + d] - ms);
    }
    float it = 1.f / st, is = 1.f / ss;
    for (int c = 0; c < 256; c++)
        mb[c * 256 + d] = expf(gtb[c * 256 + d] - mt) * it +
                          expf(gsb[c * 256 + d] - ms) * is;
}

// final cast: d_out = concat(out_t, out_s) in detected output dtype
__global__ void cast_out_k(const float* __restrict__ t, const float* __restrict__ s,
                           void* __restrict__ out, long nt, long ntot,
                           const int* __restrict__ flag)
{
    long idx = (long)blockIdx.x * 256 + threadIdx.x;
    if (idx >= ntot) return;
    float v = (idx < nt) ? t[idx] : s[idx - nt];
    if (*flag) ((float*)out)[idx] = v;
    else       ((bf16*)out)[idx] = __float2bfloat16(v);
}

// ---------------------------------------------------------------------------
// Bilinear sampler, single tap (fp32 out) — s-side. grid (N/64, B), blk 256.
// ---------------------------------------------------------------------------
__global__ void sample_k(const float* __restrict__ X, const float* __restrict__ OO,
                         float* __restrict__ S, int H, int W, int ktap)
{
    const int b = blockIdx.y;
    const int p0 = blockIdx.x * 64;
    const int tid = threadIdx.x;
    const int N = H * W;
    __shared__ float wgt[64][4];
    __shared__ int adr[64][4];
    if (tid < 64) {
        int p = p0 + tid;
        int h = p / W, w = p % W;
        const float* oob = OO + (long)b * 27 * N;
        float oy = oob[(2 * ktap) * N + p];
        float ox = oob[(2 * ktap + 1) * N + p];
        float mz = oob[(18 + ktap) * N + p];
        float mask = 1.f / (1.f + expf(-mz));
        float y = (float)(h - 1 + ktap / 3) + oy;
        float x = (float)(w - 1 + ktap % 3) + ox;
        float y0 = floorf(y), x0 = floorf(x);
        float wy = y - y0, wx = x - x0;
        float ys[2] = {y0, y0 + 1.f};
        float xs[2] = {x0, x0 + 1.f};
        float wys[2] = {1.f - wy, wy};
        float wxs[2] = {1.f - wx, wx};
#pragma unroll
        for (int iy = 0; iy < 2; iy++)
#pragma unroll
            for (int ix = 0; ix < 2; ix++) {
                float yy = ys[iy], xx = xs[ix];
                bool valid = (yy >= 0.f) && (yy <= (float)(H - 1)) &&
                             (xx >= 0.f) && (xx <= (float)(W - 1));
                float wv = valid ? wys[iy] * wxs[ix] * mask : 0.f;
                int yc = (int)fminf(fmaxf(yy, 0.f), (float)(H - 1));
                int xc = (int)fminf(fmaxf(xx, 0.f), (float)(W - 1));
                wgt[tid][iy * 2 + ix] = wv;
                adr[tid][iy * 2 + ix] = yc * W + xc;
            }
    }
    __syncthreads();
    int pl = tid & 63, cw = tid >> 6;
    float w0 = wgt[pl][0], w1 = wgt[pl][1], w2 = wgt[pl][2], w3 = wgt[pl][3];
    int a0 = adr[pl][0], a1 = adr[pl][1], a2 = adr[pl][2], a3 = adr[pl][3];
    const float* Xb = X + (long)b * 256 * N;
    float* Sb = S + (long)b * 256 * N;
    int p = p0 + pl;
    for (int c = cw; c < 256; c += 4) {
        const float* pc = Xb + (long)c * N;
        Sb[(long)c * N + p] = w0 * pc[a0] + w1 * pc[a1] + w2 * pc[a2] + w3 * pc[a3];
    }
}

// ---------------------------------------------------------------------------
// t-side: sample all 9 taps to bf16 S9[b][tap][c][n]. grid (N/64, B, 9).
// ---------------------------------------------------------------------------
__global__ void sample9_k(const float* __restrict__ X, const float* __restrict__ OO,
                          short* __restrict__ S9, int H, int W)
{
    const int b = blockIdx.y, ktap = blockIdx.z;
    const int p0 = blockIdx.x * 64;
    const int tid = threadIdx.x;
    const int N = H * W;
    __shared__ float wgt[64][4];
    __shared__ int adr[64][4];
    if (tid < 64) {
        int p = p0 + tid;
        int h = p / W, w = p % W;
        const float* oob = OO + (long)b * 27 * N;
        float oy = oob[(2 * ktap) * N + p];
        float ox = oob[(2 * ktap + 1) * N + p];
        float mz = oob[(18 + ktap) * N + p];
        float mask = 1.f / (1.f + expf(-mz));
        float y = (float)(h - 1 + ktap / 3) + oy;
        float x = (float)(w - 1 + ktap % 3) + ox;
        float y0 = floorf(y), x0 = floorf(x);
        float wy = y - y0, wx = x - x0;
        float ys[2] = {y0, y0 + 1.f};
        float xs[2] = {x0, x0 + 1.f};
        float wys[2] = {1.f - wy, wy};
        float wxs[2] = {1.f - wx, wx};
#pragma unroll
        for (int iy = 0; iy < 2; iy++)
#pragma unroll
            for (int ix = 0; ix < 2; ix++) {
                float yy = ys[iy], xx = xs[ix];
                bool valid = (yy >= 0.f) && (yy <= (float)(H - 1)) &&
                             (xx >= 0.f) && (xx <= (float)(W - 1));
                float wv = valid ? wys[iy] * wxs[ix] * mask : 0.f;
                int yc = (int)fminf(fmaxf(yy, 0.f), (float)(H - 1));
                int xc = (int)fminf(fmaxf(xx, 0.f), (float)(W - 1));
                wgt[tid][iy * 2 + ix] = wv;
                adr[tid][iy * 2 + ix] = yc * W + xc;
            }
    }
    __syncthreads();
    int pl = tid & 63, cw = tid >> 6;
    float w0 = wgt[pl][0], w1 = wgt[pl][1], w2 = wgt[pl][2], w3 = wgt[pl][3];
    int a0 = adr[pl][0], a1 = adr[pl][1], a2 = adr[pl][2], a3 = adr[pl][3];
    const float* Xb = X + (long)b * 256 * N;
    short* Sb = S9 + ((long)(b * 9 + ktap) * 256) * N;
    int p = p0 + pl;
    for (int c = cw; c < 256; c += 4) {
        const float* pc = Xb + (long)c * N;
        Sb[(long)c * N + p] = f2b(w0 * pc[a0] + w1 * pc[a1] + w2 * pc[a2] + w3 * pc[a3]);
    }
}

// ---------------------------------------------------------------------------
extern "C" void kernel_launch(void* const* d_in, const int* in_sizes, int n_in,
                              void* d_out, int out_size, void* d_ws, size_t ws_size,
                              hipStream_t stream)
{
    const int B = 16, C = 256;
    const int Nt = 256, Ns = 1024;  // 16x16, 32x32
    const long sXt = (long)C * Nt, sXs = (long)C * Ns;
    dim3 blk(256);

    float* ws = (float*)d_ws;
    int* flag = (int*)d_ws;
    long off = 16;
    auto alloc = [&](long n) { float* p = ws + off; off += n; return p; };

    float* xt32     = alloc((long)B * C * Nt);
    float* xs32     = alloc((long)B * C * Ns);   // -> out_s_f32
    float* Wf       = alloc(1470464);
    float* q_t      = alloc((long)B * 32 * Nt);
    float* k_t      = alloc((long)B * 32 * Nt);
    float* v_t      = alloc((long)B * C * Nt);
    float* q_s      = alloc((long)B * 32 * Ns);
    float* k_s      = alloc((long)B * 32 * Ns);
    float* v_s      = alloc((long)B * C * Ns);   // -> S_s
    float* gram_t   = alloc((long)B * C * C);    // -> out_t_f32
    float* gram_s   = alloc((long)B * C * C);
    float* Mc       = alloc((long)B * C * C);
    float* att_t    = alloc((long)B * Nt * Nt);  // -> S9t (with att_slab)
    float* att_slab = alloc((long)B * Ns * 256);
    float* at       = alloc((long)B * C * Nt);
    float* asr      = alloc((long)B * C * Ns);
    float* oo_t     = alloc((long)B * 27 * Nt);
    float* oo_s     = alloc((long)B * 27 * Ns);

    float* out_t_f32 = gram_t;              // dead after gram_sm
    float* out_s_f32 = xs32;                // dead after s-side pre-DCN reads
    float* S_s       = v_s;                 // dead after slab applies
    short* S9t       = (short*)att_t;       // region att_t+att_slab

    // ---- 0) detect storage dtype ----
    detect_k<<<dim3(1), blk, 0, stream>>>((const unsigned short*)d_in[0], flag);

    // ---- 1) fused ingest ----
    long woff[22];
    {
        long acc = 0;
        for (int i = 2; i < 22; i++) { woff[i] = acc; acc += (in_sizes[i] + 7) & ~7L; }
    }
    IArgs ia;
    long tot = 0;
    auto seg = [&](int s, const void* src, float* dst, long n) {
        ia.src[s] = src; ia.dst[s] = dst; ia.start[s] = tot; tot += n;
    };
    seg(0, d_in[0], xt32, (long)B * C * Nt);
    seg(1, d_in[0], at,   (long)B * C * Nt);
    seg(2, d_in[1], xs32, (long)B * C * Ns);
    seg(3, d_in[1], asr,  (long)B * C * Ns);
    for (int i = 2; i < 22; i++) seg(2 + i, d_in[i], Wf + woff[i], in_sizes[i]);
    ia.start[NSEG] = tot;
    ingest_all_k<<<dim3((unsigned)((tot + 255) / 256)), blk, 0, stream>>>(ia, flag);

    const float *tq_w = Wf + woff[2],  *tq_b = Wf + woff[3];
    const float *tk_w = Wf + woff[4],  *tk_b = Wf + woff[5];
    const float *tv_w = Wf + woff[6],  *tv_b = Wf + woff[7];
    const float *sq_w = Wf + woff[8],  *sq_b = Wf + woff[9];
    const float *sk_w = Wf + woff[10], *sk_b = Wf + woff[11];
    const float *sv_w = Wf + woff[12], *sv_b = Wf + woff[13];
    const float *t_off_w = Wf + woff[14], *t_off_b = Wf + woff[15];
    const float *t_dcn_w = Wf + woff[16], *t_dcn_b = Wf + woff[17];
    const float *s_off_w = Wf + woff[18], *s_off_b = Wf + woff[19];
    const float *s_dcn_w = Wf + woff[20], *s_dcn_b = Wf + woff[21];

    // ---- 2) q,k,v projections ----
    mgemm<false, 0, false, true, 1><<<dim3(Nt / 64, 1, B), blk, 0, stream>>>(
        tq_w, 256, 1, 0, xt32, Nt, sXt, q_t, Nt, (long)32 * Nt, tq_b, 32, Nt, 256, 0, 0);
    mgemm<false, 0, false, true, 1><<<dim3(Nt / 64, 1, B), blk, 0, stream>>>(
        tk_w, 256, 1, 0, xt32, Nt, sXt, k_t, Nt, (long)32 * Nt, tk_b, 32, Nt, 256, 0, 0);
    mgemm<false, 0, false, true, 1><<<dim3(Nt / 64, 4, B), blk, 0, stream>>>(
        tv_w, 256, 1, 0, xt32, Nt, sXt, v_t, Nt, sXt, tv_b, 256, Nt, 256, 0, 0);
    mgemm<false, 0, false, true, 2><<<dim3(Ns / 64, 1, B), blk, 0, stream>>>(
        sq_w, 256, 1, 0, xs32, Ns, sXs, q_s, Ns, (long)32 * Ns, sq_b, 32, Ns, 256, 0, 0);
    mgemm<false, 0, false, true, 2><<<dim3(Ns / 64, 1, B), blk, 0, stream>>>(
        sk_w, 256, 1, 0, xs32, Ns, sXs, k_s, Ns, (long)32 * Ns, sk_b, 32, Ns, 256, 0, 0);
    mgemm<false, 0, false, true, 2><<<dim3(Ns / 64, 4, B), blk, 0, stream>>>(
        sv_w, 256, 1, 0, xs32, Ns, sXs, v_s, Ns, sXs, sv_b, 256, Ns, 256, 0, 0);

    // ---- 3) gram matrices ----
    mgemm<false, 1, false, false, 1><<<dim3(4, 4, B), blk, 0, stream>>>(
        xt32, Nt, 1, sXt, xt32, Nt, sXt, gram_t, 256, (long)C * C, nullptr, 256, 256, Nt, 0, 0);
    mgemm<false, 1, false, false, 1><<<dim3(4, 4, B), blk, 0, stream>>>(
        xs32, Ns, 1, sXs, xs32, Ns, sXs, gram_s, 256, (long)C * C, nullptr, 256, 256, Ns, 0, 0);

    // ---- 4) M = softmax_c(gram_t) + softmax_c(gram_s) ----
    gram_sm_k<<<dim3(B, 4), dim3(64), 0, stream>>>(gram_t, gram_s, Mc);

    // ---- 5) channel attention: at += M@x_t; asr += M@x_s ----
    mgemm<false, 0, true, false, 1><<<dim3(Nt / 64, 4, B), blk, 0, stream>>>(
        Mc, 256, 1, (long)C * C, xt32, Nt, sXt, at, Nt, sXt, nullptr, 256, Nt, 256, 0, 0);
    mgemm<false, 0, true, false, 2><<<dim3(Ns / 64, 4, B), blk, 0, stream>>>(
        Mc, 256, 1, (long)C * C, xs32, Ns, sXs, asr, Ns, sXs, nullptr, 256, Ns, 256, 0, 0);

    // ---- 6) template spatial attention ----
    mgemm<true, 0, false, false, 1><<<dim3(4, 4, B), blk, 0, stream>>>(
        q_t, Nt, 1, (long)32 * Nt, k_t, Nt, (long)32 * Nt, att_t, Nt, (long)Nt * Nt,
        nullptr, Nt, Nt, 32, 0, 0);
    softmax_b_k<<<dim3((Nt * Nt) / 256), blk, 0, stream>>>(att_t, (long)Nt * Nt);
    mgemm<false, 0, true, false, 1><<<dim3(Nt / 64, 4, B), blk, 0, stream>>>(
        v_t, Nt, 1, sXt, att_t, Nt, (long)Nt * Nt, at, Nt, sXt, nullptr, 256, Nt, Nt, 0, 0);

    // ---- 7) search spatial attention, 4 m-slabs of 256 ----
    for (int m0s = 0; m0s < Ns; m0s += 256) {
        mgemm<true, 0, false, false, 2><<<dim3(4, 16, B), blk, 0, stream>>>(
            q_s, Ns, 1, (long)32 * Ns, k_s + m0s, Ns, (long)32 * Ns,
            att_slab, 256, (long)Ns * 256, nullptr, Ns, 256, 32, 0, 0);
        softmax_b_k<<<dim3((Ns * 256) / 256), blk, 0, stream>>>(att_slab, (long)Ns * 256);
        mgemm<false, 0, true, false, 2><<<dim3(4, 4, B), blk, 0, stream>>>(
            v_s, Ns, 1, sXs, att_slab, 256, (long)Ns * 256,
            asr + m0s, Ns, sXs, nullptr, 256, 256, Ns, 0, 0);
    }

    // ---- 8) offset convs as implicit-im2col GEMM (M=27, K=2304) ----
    mgemm<false, 3, false, true, 1><<<dim3(Nt / 64, 1, B), blk, 0, stream>>>(
        t_off_w, 2304, 1, 0, at, Nt, sXt, oo_t, Nt, (long)27 * Nt,
        t_off_b, 27, Nt, 2304, 16, 4);
    mgemm<false, 3, false, true, 2><<<dim3(Ns / 64, 1, B), blk, 0, stream>>>(
        s_off_w, 2304, 1, 0, asr, Ns, sXs, oo_s, Ns, (long)27 * Ns,
        s_off_b, 27, Ns, 2304, 32, 5);

    // ---- 9) t-side DCN: sample 9 taps (bf16) + one K=2304 GEMM ----
    sample9_k<<<dim3(Nt / 64, B, 9), blk, 0, stream>>>(at, oo_t, S9t, 16, 16);
    mgemm<false, 4, false, true, 1><<<dim3(Nt / 64, 4, B), blk, 0, stream>>>(
        t_dcn_w, 2304, 1, 0, S9t, Nt, (long)9 * 256 * Nt, out_t_f32, Nt, sXt,
        t_dcn_b, 256, Nt, 2304, 0, 0);

    // ---- 10) s-side DCN: 9 x (sample + accumulate GEMM), split precision ----
    for (int k = 0; k < 9; k++) {
        sample_k<<<dim3(Ns / 64, B), blk, 0, stream>>>(asr, oo_s, S_s, 32, 32, k);
        if (k == 0)
            mgemm<false, 0, false, true, 2><<<dim3(Ns / 64, 4, B), blk, 0, stream>>>(
                s_dcn_w + k, 2304, 9, 0, S_s, Ns, sXs, out_s_f32, Ns, sXs,
                s_dcn_b, 256, Ns, 256, 0, 0);
        else
            mgemm<false, 0, true, false, 2><<<dim3(Ns / 64, 4, B), blk, 0, stream>>>(
                s_dcn_w + k, 2304, 9, 0, S_s, Ns, sXs, out_s_f32, Ns, sXs,
                nullptr, 256, Ns, 256, 0, 0);
    }

    // ---- 11) emit output ----
    long nt = (long)B * C * Nt;
    long ntot = nt + (long)B * C * Ns;
    cast_out_k<<<dim3((unsigned)((ntot + 255) / 256)), blk, 0, stream>>>(
        out_t_f32, out_s_f32, d_out, nt, ntot, flag);
}

// Round 6
// 1538.475 us; speedup vs baseline: 1.9945x; 1.1880x over previous
//
#include <hip/hip_runtime.h>
#include <hip/hip_bf16.h>

typedef __hip_bfloat16 bf16;
typedef __attribute__((ext_vector_type(8))) short short8;
typedef __attribute__((ext_vector_type(4))) float f32x4;

__device__ __forceinline__ short f2b(float v)
{
    union { bf16 b; short s; } u;
    u.b = __float2bfloat16(v);
    return u.s;
}
__device__ __forceinline__ float b2f(short s)
{
    union { short s; bf16 b; } u;
    u.s = s;
    return __bfloat162float(u.b);
}
// split fp32 -> (hi, lo) bf16 pair; hi+lo carries ~16 mantissa bits
__device__ __forceinline__ void splt(float v, short& hi, short& lo)
{
    hi = f2b(v);
    lo = f2b(v - b2f(hi));
}

// ---------------------------------------------------------------------------
// Dtype detector (validated r2): flag=1 -> fp32 storage, 0 -> bf16.
// ---------------------------------------------------------------------------
__global__ void detect_k(const unsigned short* __restrict__ p, int* __restrict__ flag)
{
    __shared__ int cnt;
    if (threadIdx.x == 0) cnt = 0;
    __syncthreads();
    int bad = 0;
    for (int i = threadIdx.x; i < 4096; i += 256) {
        unsigned short u = p[2 * i];
        int e = (u >> 7) & 0xFF;
        if (e != 0 && (e < 100 || e > 140)) bad++;
    }
    atomicAdd(&cnt, bad);
    __syncthreads();
    if (threadIdx.x == 0) *flag = (cnt > 1024) ? 1 : 0;
}

// ---------------------------------------------------------------------------
// Fused ingest (validated r5)
// ---------------------------------------------------------------------------
#define NSEG 24
struct IArgs {
    const void* src[NSEG];
    float* dst[NSEG];
    long start[NSEG + 1];
};

__global__ void ingest_all_k(IArgs a, const int* __restrict__ flag)
{
    long i = (long)blockIdx.x * 256 + threadIdx.x;
    if (i >= a.start[NSEG]) return;
    int s = 0;
#pragma unroll
    for (int j = 1; j < NSEG; j++) s += (i >= a.start[j]) ? 1 : 0;
    long idx = i - a.start[s];
    float v;
    if (*flag) v = ((const float*)a.src[s])[idx];
    else       v = __bfloat162float(((const bf16*)a.src[s])[idx]);
    a.dst[s][idx] = v;
}

// C[b][m][n] = bias[m] (or 0 if bias==nullptr).  total = B*MN elements.
__global__ void fill_k(float* __restrict__ C, const float* __restrict__ bias,
                       long MN, int Nn, long total)
{
    long i = (long)blockIdx.x * 256 + threadIdx.x;
    if (i >= total) return;
    float v = 0.f;
    if (bias) {
        long r = i % MN;
        v = bias[(int)(r / Nn)];
    }
    C[i] = v;
}

// ---------------------------------------------------------------------------
// MFMA bf16 GEMM.  C[b](MxN) (+)= A_eff[b](MxK) @ B_eff[b](KxN) (+bias[m])
// A_eff[m][k] = TRA ? A[k*lda+m] : A[m*lda + k*ksA]          (fp32 source)
// B modes:
//   0: B[k*ldb + n]  (fp32)
//   1: B[n*ldb + k]  (fp32, TRB)
//   3: im2col k=(c*9+tap): X[c*ldb + shift_tap(n)] (fp32, 3x3 SAME, W=2^wsh)
//   4: tap9 k=(c*9+tap): hi from Bsrc[(tap*256+c)*ldb+n], lo from Bsrc2 (bf16)
// PREC=1 plain bf16; PREC=2 split hi/lo (Ahi*Bhi + Ahi*Blo + Alo*Bhi).
// KSPLIT>1: blockIdx.y = mtile*KSPLIT + chunk; epilogue atomicAdd into
// pre-initialized C (BIAS/ACCUM ignored at those call sites).
// All LDS staging writes are contiguous short8 (b128) at pitch 40 -> no bank
// conflicts (r5 counter: 2e7 conflicts from scalar transpose writes).
// ---------------------------------------------------------------------------
template <bool TRA, int BMODE, bool ACCUM, bool BIAS, int PREC, int KSPLIT>
__launch_bounds__(256)
__global__ void mgemm(const float* __restrict__ A, int lda, int ksA, long sA,
                      const void* __restrict__ Bsrc, const void* __restrict__ Bsrc2,
                      int ldb, long sB,
                      float* __restrict__ C, int ldc, long sC,
                      const float* __restrict__ bias,
                      int M, int N, int K, int H, int wsh)
{
    __shared__ short As[PREC * 2560];  // [part][64][40]
    __shared__ short Bs[PREC * 2560];

    const int bz = blockIdx.z;
    const float* Ab = A + (long)bz * sA;
    float* Cb = C + (long)bz * sC;
    const int mt = blockIdx.y / KSPLIT, ch = blockIdx.y % KSPLIT;
    const int m0 = mt * 64, n0 = blockIdx.x * 64;
    const int kchunk = K / KSPLIT;
    const int kbeg = ch * kchunk, kend = kbeg + kchunk;
    const int tid = threadIdx.x;

    f32x4 acc[2][2];
#pragma unroll
    for (int i = 0; i < 2; i++)
#pragma unroll
        for (int j = 0; j < 2; j++) acc[i][j] = (f32x4){0.f, 0.f, 0.f, 0.f};

    const int lane = tid & 63, wv = tid >> 6;
    const int moff = (wv & 1) * 32, noff = (wv >> 1) * 32;
    const int lr = lane & 15, lq = lane >> 4;

    const int mm = tid >> 2;            // row (A) / col (B) owner
    const int kk0 = (tid & 3) * 8;      // 8-wide k group

    for (int k0 = kbeg; k0 < kend; k0 += 32) {
        // ---- stage A: m-major, short8 write ----
        {
            float vv[8];
            if (m0 + mm < M) {
                if (!TRA) {
                    if (ksA == 1) {
                        const float4* s4 = (const float4*)(Ab + (long)(m0 + mm) * lda + k0 + kk0);
                        float4 v0 = s4[0], v1 = s4[1];
                        vv[0] = v0.x; vv[1] = v0.y; vv[2] = v0.z; vv[3] = v0.w;
                        vv[4] = v1.x; vv[5] = v1.y; vv[6] = v1.z; vv[7] = v1.w;
                    } else {
                        const float* s = Ab + (long)(m0 + mm) * lda + (long)(k0 + kk0) * ksA;
#pragma unroll
                        for (int j = 0; j < 8; j++) vv[j] = s[(long)j * ksA];
                    }
                } else {
#pragma unroll
                    for (int j = 0; j < 8; j++)
                        vv[j] = Ab[(long)(k0 + kk0 + j) * lda + m0 + mm];
                }
            } else {
#pragma unroll
                for (int j = 0; j < 8; j++) vv[j] = 0.f;
            }
            short8 hi, lo;
#pragma unroll
            for (int j = 0; j < 8; j++) { short h, l; splt(vv[j], h, l); hi[j] = h; lo[j] = l; }
            *(short8*)&As[mm * 40 + kk0] = hi;
            if (PREC == 2) *(short8*)&As[2560 + mm * 40 + kk0] = lo;
        }

        // ---- stage B: n-major, short8 write ----
        if (BMODE == 1) {
            const float4* s4 = (const float4*)((const float*)Bsrc + (long)bz * sB +
                                               (long)(n0 + mm) * ldb + k0 + kk0);
            float4 v0 = s4[0], v1 = s4[1];
            float vv[8] = {v0.x, v0.y, v0.z, v0.w, v1.x, v1.y, v1.z, v1.w};
            short8 hi, lo;
#pragma unroll
            for (int j = 0; j < 8; j++) { short h, l; splt(vv[j], h, l); hi[j] = h; lo[j] = l; }
            *(short8*)&Bs[mm * 40 + kk0] = hi;
            if (PREC == 2) *(short8*)&Bs[2560 + mm * 40 + kk0] = lo;
        } else if (BMODE == 4) {
            short8 hi, lo;
#pragma unroll
            for (int j = 0; j < 8; j++) {
                int kc = k0 + kk0 + j;
                int c = kc / 9, tap = kc - 9 * c;
                long o = (long)bz * sB + (long)(tap * 256 + c) * ldb + n0 + mm;
                hi[j] = ((const short*)Bsrc)[o];
                lo[j] = (PREC == 2) ? ((const short*)Bsrc2)[o] : (short)0;
            }
            *(short8*)&Bs[mm * 40 + kk0] = hi;
            if (PREC == 2) *(short8*)&Bs[2560 + mm * 40 + kk0] = lo;
        } else {
            float vv[8];
            if (BMODE == 0) {
#pragma unroll
                for (int j = 0; j < 8; j++)
                    vv[j] = ((const float*)Bsrc)[(long)bz * sB + (long)(k0 + kk0 + j) * ldb + n0 + mm];
            } else {  // BMODE 3: im2col
                int W = 1 << wsh;
                int n = n0 + mm;
                int hbase = n >> wsh, wbase = n & (W - 1);
#pragma unroll
                for (int j = 0; j < 8; j++) {
                    int kc = k0 + kk0 + j;
                    int c = kc / 9, tap = kc - 9 * c;
                    int h = hbase + tap / 3 - 1, w = wbase + tap % 3 - 1;
                    vv[j] = (h >= 0 && h < H && w >= 0 && w < W)
                          ? ((const float*)Bsrc)[(long)bz * sB + (long)c * ldb + (h << wsh) + w]
                          : 0.f;
                }
            }
            short8 hi, lo;
#pragma unroll
            for (int j = 0; j < 8; j++) { short h, l; splt(vv[j], h, l); hi[j] = h; lo[j] = l; }
            *(short8*)&Bs[mm * 40 + kk0] = hi;
            if (PREC == 2) *(short8*)&Bs[2560 + mm * 40 + kk0] = lo;
        }
        __syncthreads();

        // ---- compute ----
        short8 a0h = *(short8*)&As[(moff + lr) * 40 + lq * 8];
        short8 a1h = *(short8*)&As[(moff + 16 + lr) * 40 + lq * 8];
        short8 b0h = *(short8*)&Bs[(noff + lr) * 40 + lq * 8];
        short8 b1h = *(short8*)&Bs[(noff + 16 + lr) * 40 + lq * 8];
        acc[0][0] = __builtin_amdgcn_mfma_f32_16x16x32_bf16(a0h, b0h, acc[0][0], 0, 0, 0);
        acc[0][1] = __builtin_amdgcn_mfma_f32_16x16x32_bf16(a0h, b1h, acc[0][1], 0, 0, 0);
        acc[1][0] = __builtin_amdgcn_mfma_f32_16x16x32_bf16(a1h, b0h, acc[1][0], 0, 0, 0);
        acc[1][1] = __builtin_amdgcn_mfma_f32_16x16x32_bf16(a1h, b1h, acc[1][1], 0, 0, 0);
        if (PREC == 2) {
            short8 a0l = *(short8*)&As[2560 + (moff + lr) * 40 + lq * 8];
            short8 a1l = *(short8*)&As[2560 + (moff + 16 + lr) * 40 + lq * 8];
            short8 b0l = *(short8*)&Bs[2560 + (noff + lr) * 40 + lq * 8];
            short8 b1l = *(short8*)&Bs[2560 + (noff + 16 + lr) * 40 + lq * 8];
            acc[0][0] = __builtin_amdgcn_mfma_f32_16x16x32_bf16(a0h, b0l, acc[0][0], 0, 0, 0);
            acc[0][1] = __builtin_amdgcn_mfma_f32_16x16x32_bf16(a0h, b1l, acc[0][1], 0, 0, 0);
            acc[1][0] = __builtin_amdgcn_mfma_f32_16x16x32_bf16(a1h, b0l, acc[1][0], 0, 0, 0);
            acc[1][1] = __builtin_amdgcn_mfma_f32_16x16x32_bf16(a1h, b1l, acc[1][1], 0, 0, 0);
            acc[0][0] = __builtin_amdgcn_mfma_f32_16x16x32_bf16(a0l, b0h, acc[0][0], 0, 0, 0);
            acc[0][1] = __builtin_amdgcn_mfma_f32_16x16x32_bf16(a0l, b1h, acc[0][1], 0, 0, 0);
            acc[1][0] = __builtin_amdgcn_mfma_f32_16x16x32_bf16(a1l, b0h, acc[1][0], 0, 0, 0);
            acc[1][1] = __builtin_amdgcn_mfma_f32_16x16x32_bf16(a1l, b1h, acc[1][1], 0, 0, 0);
        }
        __syncthreads();
    }

    // ---- epilogue ----
#pragma unroll
    for (int mi = 0; mi < 2; mi++)
#pragma unroll
        for (int ni = 0; ni < 2; ni++) {
            int col = n0 + noff + ni * 16 + lr;
#pragma unroll
            for (int r = 0; r < 4; r++) {
                int row = m0 + moff + mi * 16 + lq * 4 + r;
                if (row < M) {
                    long o = (long)row * ldc + col;
                    float v = acc[mi][ni][r];
                    if (KSPLIT > 1) {
                        atomicAdd(&Cb[o], v);
                    } else {
                        if (BIAS) v += bias[row];
                        if (ACCUM) v += Cb[o];
                        Cb[o] = v;
                    }
                }
            }
        }
}

// Softmax over batch axis (16) of att[b][idx]
__global__ void softmax_b_k(float* __restrict__ att, long NN)
{
    long idx = (long)blockIdx.x * 256 + threadIdx.x;
    if (idx >= NN) return;
    float r[16];
    float mx = -1e30f;
#pragma unroll
    for (int b = 0; b < 16; b++) {
        r[b] = att[(long)b * NN + idx];
        mx = fmaxf(mx, r[b]);
    }
    float s = 0.f;
#pragma unroll
    for (int b = 0; b < 16; b++) { r[b] = expf(r[b] - mx); s += r[b]; }
    float inv = 1.f / s;
#pragma unroll
    for (int b = 0; b < 16; b++) att[(long)b * NN + idx] = r[b] * inv;
}

// M[b][c][d] = softmax_c(gram_t) + softmax_c(gram_s)
__global__ void gram_sm_k(const float* __restrict__ gt, const float* __restrict__ gs,
                          float* __restrict__ Mo)
{
    int b = blockIdx.x;
    int d = blockIdx.y * 64 + threadIdx.x;
    const float* gtb = gt + (long)b * 65536;
    const float* gsb = gs + (long)b * 65536;
    float* mb = Mo + (long)b * 65536;
    float mt = -1e30f, ms = -1e30f;
    for (int c = 0; c < 256; c++) {
        mt = fmaxf(mt, gtb[c * 256 + d]);
        ms = fmaxf(ms, gsb[c * 256 + d]);
    }
    float st = 0.f, ss = 0.f;
    for (int c = 0; c < 256; c++) {
        st += expf(gtb[c * 256 + d] - mt);
        ss += expf(gsb[c * 256 + d] - ms);
    }
    float it = 1.f / st, is = 1.f / ss;
    for (int c = 0; c < 256; c++)
        mb[c * 256 + d] = expf(gtb[c * 256 + d] - mt) * it +
                          expf(gsb[c * 256 + d] - ms) * is;
}

// final cast: d_out = concat(out_t, out_s) in detected output dtype
__global__ void cast_out_k(const float* __restrict__ t, const float* __restrict__ s,
                           void* __restrict__ out, long nt, long ntot,
                           const int* __restrict__ flag)
{
    long idx = (long)blockIdx.x * 256 + threadIdx.x;
    if (idx >= ntot) return;
    float v = (idx < nt) ? t[idx] : s[idx - nt];
    if (*flag) ((float*)out)[idx] = v;
    else       ((bf16*)out)[idx] = __float2bfloat16(v);
}

// ---------------------------------------------------------------------------
// Bilinear sampler, single tap (fp32 out) — s-side. grid (N/64, B), blk 256.
// ---------------------------------------------------------------------------
__global__ void sample_k(const float* __restrict__ X, const float* __restrict__ OO,
                         float* __restrict__ S, int H, int W, int ktap)
{
    const int b = blockIdx.y;
    const int p0 = blockIdx.x * 64;
    const int tid = threadIdx.x;
    const int N = H * W;
    __shared__ float wgt[64][4];
    __shared__ int adr[64][4];
    if (tid < 64) {
        int p = p0 + tid;
        int h = p / W, w = p % W;
        const float* oob = OO + (long)b * 27 * N;
        float oy = oob[(2 * ktap) * N + p];
        float ox = oob[(2 * ktap + 1) * N + p];
        float mz = oob[(18 + ktap) * N + p];
        float mask = 1.f / (1.f + expf(-mz));
        float y = (float)(h - 1 + ktap / 3) + oy;
        float x = (float)(w - 1 + ktap % 3) + ox;
        float y0 = floorf(y), x0 = floorf(x);
        float wy = y - y0, wx = x - x0;
        float ys[2] = {y0, y0 + 1.f};
        float xs[2] = {x0, x0 + 1.f};
        float wys[2] = {1.f - wy, wy};
        float wxs[2] = {1.f - wx, wx};
#pragma unroll
        for (int iy = 0; iy < 2; iy++)
#pragma unroll
            for (int ix = 0; ix < 2; ix++) {
                float yy = ys[iy], xx = xs[ix];
                bool valid = (yy >= 0.f) && (yy <= (float)(H - 1)) &&
                             (xx >= 0.f) && (xx <= (float)(W - 1));
                float wv = valid ? wys[iy] * wxs[ix] * mask : 0.f;
                int yc = (int)fminf(fmaxf(yy, 0.f), (float)(H - 1));
                int xc = (int)fminf(fmaxf(xx, 0.f), (float)(W - 1));
                wgt[tid][iy * 2 + ix] = wv;
                adr[tid][iy * 2 + ix] = yc * W + xc;
            }
    }
    __syncthreads();
    int pl = tid & 63, cw = tid >> 6;
    float w0 = wgt[pl][0], w1 = wgt[pl][1], w2 = wgt[pl][2], w3 = wgt[pl][3];
    int a0 = adr[pl][0], a1 = adr[pl][1], a2 = adr[pl][2], a3 = adr[pl][3];
    const float* Xb = X + (long)b * 256 * N;
    float* Sb = S + (long)b * 256 * N;
    int p = p0 + pl;
    for (int c = cw; c < 256; c += 4) {
        const float* pc = Xb + (long)c * N;
        Sb[(long)c * N + p] = w0 * pc[a0] + w1 * pc[a1] + w2 * pc[a2] + w3 * pc[a3];
    }
}

// ---------------------------------------------------------------------------
// t-side: sample all 9 taps to SPLIT bf16 (hi, lo). grid (N/64, B, 9).
// ---------------------------------------------------------------------------
__global__ void sample9_k(const float* __restrict__ X, const float* __restrict__ OO,
                          short* __restrict__ Sh, short* __restrict__ Sl,
                          int H, int W)
{
    const int b = blockIdx.y, ktap = blockIdx.z;
    const int p0 = blockIdx.x * 64;
    const int tid = threadIdx.x;
    const int N = H * W;
    __shared__ float wgt[64][4];
    __shared__ int adr[64][4];
    if (tid < 64) {
        int p = p0 + tid;
        int h = p / W, w = p % W;
        const float* oob = OO + (long)b * 27 * N;
        float oy = oob[(2 * ktap) * N + p];
        float ox = oob[(2 * ktap + 1) * N + p];
        float mz = oob[(18 + ktap) * N + p];
        float mask = 1.f / (1.f + expf(-mz));
        float y = (float)(h - 1 + ktap / 3) + oy;
        float x = (float)(w - 1 + ktap % 3) + ox;
        float y0 = floorf(y), x0 = floorf(x);
        float wy = y - y0, wx = x - x0;
        float ys[2] = {y0, y0 + 1.f};
        float xs[2] = {x0, x0 + 1.f};
        float wys[2] = {1.f - wy, wy};
        float wxs[2] = {1.f - wx, wx};
#pragma unroll
        for (int iy = 0; iy < 2; iy++)
#pragma unroll
            for (int ix = 0; ix < 2; ix++) {
                float yy = ys[iy], xx = xs[ix];
                bool valid = (yy >= 0.f) && (yy <= (float)(H - 1)) &&
                             (xx >= 0.f) && (xx <= (float)(W - 1));
                float wv = valid ? wys[iy] * wxs[ix] * mask : 0.f;
                int yc = (int)fminf(fmaxf(yy, 0.f), (float)(H - 1));
                int xc = (int)fminf(fmaxf(xx, 0.f), (float)(W - 1));
                wgt[tid][iy * 2 + ix] = wv;
                adr[tid][iy * 2 + ix] = yc * W + xc;
            }
    }
    __syncthreads();
    int pl = tid & 63, cw = tid >> 6;
    float w0 = wgt[pl][0], w1 = wgt[pl][1], w2 = wgt[pl][2], w3 = wgt[pl][3];
    int a0 = adr[pl][0], a1 = adr[pl][1], a2 = adr[pl][2], a3 = adr[pl][3];
    const float* Xb = X + (long)b * 256 * N;
    long base = ((long)(b * 9 + ktap) * 256) * N;
    int p = p0 + pl;
    for (int c = cw; c < 256; c += 4) {
        const float* pc = Xb + (long)c * N;
        float v = w0 * pc[a0] + w1 * pc[a1] + w2 * pc[a2] + w3 * pc[a3];
        short h, l; splt(v, h, l);
        Sh[base + (long)c * N + p] = h;
        Sl[base + (long)c * N + p] = l;
    }
}

// ---------------------------------------------------------------------------
extern "C" void kernel_launch(void* const* d_in, const int* in_sizes, int n_in,
                              void* d_out, int out_size, void* d_ws, size_t ws_size,
                              hipStream_t stream)
{
    const int B = 16, C = 256;
    const int Nt = 256, Ns = 1024;  // 16x16, 32x32
    const long sXt = (long)C * Nt, sXs = (long)C * Ns;
    dim3 blk(256);

    float* ws = (float*)d_ws;
    int* flag = (int*)d_ws;
    long off = 16;
    auto alloc = [&](long n) { float* p = ws + off; off += n; return p; };

    float* xt32     = alloc((long)B * C * Nt);
    float* xs32     = alloc((long)B * C * Ns);   // -> out_s_f32
    float* Wf       = alloc(1470464);
    float* q_t      = alloc((long)B * 32 * Nt);
    float* k_t      = alloc((long)B * 32 * Nt);
    float* v_t      = alloc((long)B * C * Nt);
    float* q_s      = alloc((long)B * 32 * Ns);  // q_s..v_s -> S9lo region (21MB)
    float* k_s      = alloc((long)B * 32 * Ns);
    float* v_s      = alloc((long)B * C * Ns);   // -> S_s
    float* gram_t   = alloc((long)B * C * C);    // -> out_t_f32
    float* gram_s   = alloc((long)B * C * C);
    float* Mc       = alloc((long)B * C * C);
    float* att_t    = alloc((long)B * Nt * Nt);  // att_t..att_slab -> S9hi (21MB)
    float* att_slab = alloc((long)B * Ns * 256);
    float* at       = alloc((long)B * C * Nt);
    float* asr      = alloc((long)B * C * Ns);
    float* oo_t     = alloc((long)B * 27 * Nt);
    float* oo_s     = alloc((long)B * 27 * Ns);

    float* out_t_f32 = gram_t;        // dead after gram_sm + prefill
    float* out_s_f32 = xs32;          // dead after channel-s apply
    float* S_s       = v_s;           // dead after slab applies
    short* S9h       = (short*)att_t; // att region dead after applies (need 18.9MB of 21)
    short* S9l       = (short*)q_s;   // q_s..v_s dead after slabs/DCN-s (need 18.9 of 21)

    // ---- 0) detect storage dtype ----
    detect_k<<<dim3(1), blk, 0, stream>>>((const unsigned short*)d_in[0], flag);

    // ---- 1) fused ingest ----
    long woff[22];
    {
        long acc = 0;
        for (int i = 2; i < 22; i++) { woff[i] = acc; acc += (in_sizes[i] + 7) & ~7L; }
    }
    IArgs ia;
    long tot = 0;
    auto seg = [&](int s, const void* src, float* dst, long n) {
        ia.src[s] = src; ia.dst[s] = dst; ia.start[s] = tot; tot += n;
    };
    seg(0, d_in[0], xt32, (long)B * C * Nt);
    seg(1, d_in[0], at,   (long)B * C * Nt);
    seg(2, d_in[1], xs32, (long)B * C * Ns);
    seg(3, d_in[1], asr,  (long)B * C * Ns);
    for (int i = 2; i < 22; i++) seg(2 + i, d_in[i], Wf + woff[i], in_sizes[i]);
    ia.start[NSEG] = tot;
    ingest_all_k<<<dim3((unsigned)((tot + 255) / 256)), blk, 0, stream>>>(ia, flag);

    const float *tq_w = Wf + woff[2],  *tq_b = Wf + woff[3];
    const float *tk_w = Wf + woff[4],  *tk_b = Wf + woff[5];
    const float *tv_w = Wf + woff[6],  *tv_b = Wf + woff[7];
    const float *sq_w = Wf + woff[8],  *sq_b = Wf + woff[9];
    const float *sk_w = Wf + woff[10], *sk_b = Wf + woff[11];
    const float *sv_w = Wf + woff[12], *sv_b = Wf + woff[13];
    const float *t_off_w = Wf + woff[14], *t_off_b = Wf + woff[15];
    const float *t_dcn_w = Wf + woff[16], *t_dcn_b = Wf + woff[17];
    const float *s_off_w = Wf + woff[18], *s_off_b = Wf + woff[19];
    const float *s_dcn_w = Wf + woff[20], *s_dcn_b = Wf + woff[21];

    // ---- 2) pre-inits for K-split targets ----
    fill_k<<<dim3((2 * B * C * C) / 256), blk, 0, stream>>>(gram_t, nullptr, 1, 1, 2L * B * C * C);
    fill_k<<<dim3((B * 27 * Nt + 255) / 256), blk, 0, stream>>>(oo_t, t_off_b, 27L * Nt, Nt, (long)B * 27 * Nt);
    fill_k<<<dim3((B * 27 * Ns + 255) / 256), blk, 0, stream>>>(oo_s, s_off_b, 27L * Ns, Ns, (long)B * 27 * Ns);

    // ---- 3) q,k,v projections (all PREC2) ----
    mgemm<false, 0, false, true, 2, 1><<<dim3(Nt / 64, 1, B), blk, 0, stream>>>(
        tq_w, 256, 1, 0, xt32, nullptr, Nt, sXt, q_t, Nt, (long)32 * Nt, tq_b, 32, Nt, 256, 0, 0);
    mgemm<false, 0, false, true, 2, 1><<<dim3(Nt / 64, 1, B), blk, 0, stream>>>(
        tk_w, 256, 1, 0, xt32, nullptr, Nt, sXt, k_t, Nt, (long)32 * Nt, tk_b, 32, Nt, 256, 0, 0);
    mgemm<false, 0, false, true, 2, 1><<<dim3(Nt / 64, 4, B), blk, 0, stream>>>(
        tv_w, 256, 1, 0, xt32, nullptr, Nt, sXt, v_t, Nt, sXt, tv_b, 256, Nt, 256, 0, 0);
    mgemm<false, 0, false, true, 2, 1><<<dim3(Ns / 64, 1, B), blk, 0, stream>>>(
        sq_w, 256, 1, 0, xs32, nullptr, Ns, sXs, q_s, Ns, (long)32 * Ns, sq_b, 32, Ns, 256, 0, 0);
    mgemm<false, 0, false, true, 2, 1><<<dim3(Ns / 64, 1, B), blk, 0, stream>>>(
        sk_w, 256, 1, 0, xs32, nullptr, Ns, sXs, k_s, Ns, (long)32 * Ns, sk_b, 32, Ns, 256, 0, 0);
    mgemm<false, 0, false, true, 2, 1><<<dim3(Ns / 64, 4, B), blk, 0, stream>>>(
        sv_w, 256, 1, 0, xs32, nullptr, Ns, sXs, v_s, Ns, sXs, sv_b, 256, Ns, 256, 0, 0);

    // ---- 4) gram matrices (K-split 4, atomic into zeroed buffers) ----
    mgemm<false, 1, false, false, 1, 4><<<dim3(4, 16, B), blk, 0, stream>>>(
        xt32, Nt, 1, sXt, xt32, nullptr, Nt, sXt, gram_t, 256, (long)C * C, nullptr, 256, 256, Nt, 0, 0);
    mgemm<false, 1, false, false, 1, 4><<<dim3(4, 16, B), blk, 0, stream>>>(
        xs32, Ns, 1, sXs, xs32, nullptr, Ns, sXs, gram_s, 256, (long)C * C, nullptr, 256, 256, Ns, 0, 0);

    // ---- 5) M = softmax_c(gram_t) + softmax_c(gram_s) ----
    gram_sm_k<<<dim3(B, 4), dim3(64), 0, stream>>>(gram_t, gram_s, Mc);

    // ---- 6) channel attention: at += M@x_t (split2); asr += M@x_s ----
    mgemm<false, 0, true, false, 2, 2><<<dim3(Nt / 64, 8, B), blk, 0, stream>>>(
        Mc, 256, 1, (long)C * C, xt32, nullptr, Nt, sXt, at, Nt, sXt, nullptr, 256, Nt, 256, 0, 0);
    mgemm<false, 0, true, false, 2, 1><<<dim3(Ns / 64, 4, B), blk, 0, stream>>>(
        Mc, 256, 1, (long)C * C, xs32, nullptr, Ns, sXs, asr, Ns, sXs, nullptr, 256, Ns, 256, 0, 0);

    // ---- 7) template spatial attention ----
    mgemm<true, 0, false, false, 2, 1><<<dim3(4, 4, B), blk, 0, stream>>>(
        q_t, Nt, 1, (long)32 * Nt, k_t, nullptr, Nt, (long)32 * Nt, att_t, Nt, (long)Nt * Nt,
        nullptr, Nt, Nt, 32, 0, 0);
    softmax_b_k<<<dim3((Nt * Nt) / 256), blk, 0, stream>>>(att_t, (long)Nt * Nt);
    mgemm<false, 0, true, false, 2, 2><<<dim3(Nt / 64, 8, B), blk, 0, stream>>>(
        v_t, Nt, 1, sXt, att_t, nullptr, Nt, (long)Nt * Nt, at, Nt, sXt, nullptr, 256, Nt, Nt, 0, 0);

    // ---- 8) search spatial attention, 4 m-slabs; applies K-split 4 ----
    for (int m0s = 0; m0s < Ns; m0s += 256) {
        mgemm<true, 0, false, false, 2, 1><<<dim3(4, 16, B), blk, 0, stream>>>(
            q_s, Ns, 1, (long)32 * Ns, k_s + m0s, nullptr, Ns, (long)32 * Ns,
            att_slab, 256, (long)Ns * 256, nullptr, Ns, 256, 32, 0, 0);
        softmax_b_k<<<dim3((Ns * 256) / 256), blk, 0, stream>>>(att_slab, (long)Ns * 256);
        mgemm<false, 0, true, false, 2, 4><<<dim3(4, 16, B), blk, 0, stream>>>(
            v_s, Ns, 1, sXs, att_slab, nullptr, 256, (long)Ns * 256,
            asr + m0s, Ns, sXs, nullptr, 256, 256, Ns, 0, 0);
    }

    // ---- 9) offset convs (im2col, K-split 4, bias prefilled) ----
    mgemm<false, 3, false, false, 2, 4><<<dim3(Nt / 64, 4, B), blk, 0, stream>>>(
        t_off_w, 2304, 1, 0, at, nullptr, Nt, sXt, oo_t, Nt, (long)27 * Nt,
        nullptr, 27, Nt, 2304, 16, 4);
    mgemm<false, 3, false, false, 2, 4><<<dim3(Ns / 64, 4, B), blk, 0, stream>>>(
        s_off_w, 2304, 1, 0, asr, nullptr, Ns, sXs, oo_s, Ns, (long)27 * Ns,
        nullptr, 27, Ns, 2304, 32, 5);

    // ---- 10) s-side DCN: prefill bias, then 9 x (sample + accumulate GEMM) ----
    fill_k<<<dim3((B * C * Ns + 255) / 256), blk, 0, stream>>>(
        out_s_f32, s_dcn_b, (long)C * Ns, Ns, (long)B * C * Ns);
    for (int k = 0; k < 9; k++) {
        sample_k<<<dim3(Ns / 64, B), blk, 0, stream>>>(asr, oo_s, S_s, 32, 32, k);
        mgemm<false, 0, true, false, 2, 1><<<dim3(Ns / 64, 4, B), blk, 0, stream>>>(
            s_dcn_w + k, 2304, 9, 0, S_s, nullptr, Ns, sXs, out_s_f32, Ns, sXs,
            nullptr, 256, Ns, 256, 0, 0);
    }

    // ---- 11) t-side DCN: split-bf16 taps + one K=2304 GEMM (K-split 4) ----
    fill_k<<<dim3((B * C * Nt + 255) / 256), blk, 0, stream>>>(
        out_t_f32, t_dcn_b, (long)C * Nt, Nt, (long)B * C * Nt);
    sample9_k<<<dim3(Nt / 64, B, 9), blk, 0, stream>>>(at, oo_t, S9h, S9l, 16, 16);
    mgemm<false, 4, false, false, 2, 4><<<dim3(Nt / 64, 16, B), blk, 0, stream>>>(
        t_dcn_w, 2304, 1, 0, S9h, S9l, Nt, (long)9 * 256 * Nt, out_t_f32, Nt, sXt,
        nullptr, 256, Nt, 2304, 0, 0);

    // ---- 12) emit output ----
    long nt = (long)B * C * Nt;
    long ntot = nt + (long)B * C * Ns;
    cast_out_k<<<dim3((unsigned)((ntot + 255) / 256)), blk, 0, stream>>>(
        out_t_f32, out_s_f32, d_out, nt, ntot, flag);
}

// Round 7
// 1499.747 us; speedup vs baseline: 2.0460x; 1.0258x over previous
//
#include <hip/hip_runtime.h>
#include <hip/hip_bf16.h>

typedef __hip_bfloat16 bf16;
typedef __attribute__((ext_vector_type(8))) short short8;
typedef __attribute__((ext_vector_type(4))) float f32x4;

__device__ __forceinline__ short f2b(float v)
{
    union { bf16 b; short s; } u;
    u.b = __float2bfloat16(v);
    return u.s;
}
__device__ __forceinline__ float b2f(short s)
{
    union { short s; bf16 b; } u;
    u.s = s;
    return __bfloat162float(u.b);
}
__device__ __forceinline__ void splt(float v, short& hi, short& lo)
{
    hi = f2b(v);
    lo = f2b(v - b2f(hi));
}

// ---------------------------------------------------------------------------
// Dtype detector (validated r2): flag=1 -> fp32 storage, 0 -> bf16.
// ---------------------------------------------------------------------------
__global__ void detect_k(const unsigned short* __restrict__ p, int* __restrict__ flag)
{
    __shared__ int cnt;
    if (threadIdx.x == 0) cnt = 0;
    __syncthreads();
    int bad = 0;
    for (int i = threadIdx.x; i < 4096; i += 256) {
        unsigned short u = p[2 * i];
        int e = (u >> 7) & 0xFF;
        if (e != 0 && (e < 100 || e > 140)) bad++;
    }
    atomicAdd(&cnt, bad);
    __syncthreads();
    if (threadIdx.x == 0) *flag = (cnt > 1024) ? 1 : 0;
}

// ---------------------------------------------------------------------------
// Fused ingest (validated r5)
// ---------------------------------------------------------------------------
#define NSEG 24
struct IArgs {
    const void* src[NSEG];
    float* dst[NSEG];
    long start[NSEG + 1];
};

__global__ void ingest_all_k(IArgs a, const int* __restrict__ flag)
{
    long i = (long)blockIdx.x * 256 + threadIdx.x;
    if (i >= a.start[NSEG]) return;
    int s = 0;
#pragma unroll
    for (int j = 1; j < NSEG; j++) s += (i >= a.start[j]) ? 1 : 0;
    long idx = i - a.start[s];
    float v;
    if (*flag) v = ((const float*)a.src[s])[idx];
    else       v = __bfloat162float(((const bf16*)a.src[s])[idx]);
    a.dst[s][idx] = v;
}

// C[b][m][n] = bias[m] (or 0).  total = B*MN.
__global__ void fill_k(float* __restrict__ C, const float* __restrict__ bias,
                       long MN, int Nn, long total)
{
    long i = (long)blockIdx.x * 256 + threadIdx.x;
    if (i >= total) return;
    float v = 0.f;
    if (bias) {
        long r = i % MN;
        v = bias[(int)(r / Nn)];
    }
    C[i] = v;
}

// Tiled transpose: X[b][c][n] -> XT[b][n][c].  C=256. grid (N/32, 8, B), blk (32,8)
__global__ void tr_k(const float* __restrict__ X, float* __restrict__ XT, int N)
{
    __shared__ float t[32][33];
    int b = blockIdx.z, n0 = blockIdx.x * 32, c0 = blockIdx.y * 32;
    const float* Xb = X + (long)b * 256 * N;
    float* Tb = XT + (long)b * 256 * N;
    int tx = threadIdx.x, ty = threadIdx.y;
#pragma unroll
    for (int i = 0; i < 4; i++)
        t[ty + 8 * i][tx] = Xb[(long)(c0 + ty + 8 * i) * N + n0 + tx];
    __syncthreads();
#pragma unroll
    for (int i = 0; i < 4; i++)
        Tb[(long)(n0 + ty + 8 * i) * 256 + c0 + tx] = t[tx][ty + 8 * i];
}

// ---------------------------------------------------------------------------
// MFMA bf16 GEMM (r6 core, BMODE4 removed).
//   0: B[k*ldb+n] (fp32, scalar k-strided — used only for K=32 logits)
//   1: B[n*ldb+k] (fp32, coalesced float4 + contiguous short8 LDS writes)
//   3: im2col (3x3 SAME)
// PREC2 = split hi/lo (3 MFMA).  KSPLIT>1: atomicAdd into pre-initialized C.
// ---------------------------------------------------------------------------
template <bool TRA, int BMODE, bool ACCUM, bool BIAS, int PREC, int KSPLIT>
__launch_bounds__(256)
__global__ void mgemm(const float* __restrict__ A, int lda, int ksA, long sA,
                      const void* __restrict__ Bsrc, int ldb, long sB,
                      float* __restrict__ C, int ldc, long sC,
                      const float* __restrict__ bias,
                      int M, int N, int K, int H, int wsh)
{
    __shared__ short As[PREC * 2560];
    __shared__ short Bs[PREC * 2560];

    const int bz = blockIdx.z;
    const float* Ab = A + (long)bz * sA;
    float* Cb = C + (long)bz * sC;
    const int mt = blockIdx.y / KSPLIT, ch = blockIdx.y % KSPLIT;
    const int m0 = mt * 64, n0 = blockIdx.x * 64;
    const int kchunk = K / KSPLIT;
    const int kbeg = ch * kchunk, kend = kbeg + kchunk;
    const int tid = threadIdx.x;

    f32x4 acc[2][2];
#pragma unroll
    for (int i = 0; i < 2; i++)
#pragma unroll
        for (int j = 0; j < 2; j++) acc[i][j] = (f32x4){0.f, 0.f, 0.f, 0.f};

    const int lane = tid & 63, wv = tid >> 6;
    const int moff = (wv & 1) * 32, noff = (wv >> 1) * 32;
    const int lr = lane & 15, lq = lane >> 4;
    const int mm = tid >> 2, kk0 = (tid & 3) * 8;

    for (int k0 = kbeg; k0 < kend; k0 += 32) {
        // ---- stage A ----
        {
            float vv[8];
            if (m0 + mm < M) {
                if (!TRA) {
                    if (ksA == 1) {
                        const float4* s4 = (const float4*)(Ab + (long)(m0 + mm) * lda + k0 + kk0);
                        float4 v0 = s4[0], v1 = s4[1];
                        vv[0] = v0.x; vv[1] = v0.y; vv[2] = v0.z; vv[3] = v0.w;
                        vv[4] = v1.x; vv[5] = v1.y; vv[6] = v1.z; vv[7] = v1.w;
                    } else {
                        const float* s = Ab + (long)(m0 + mm) * lda + (long)(k0 + kk0) * ksA;
#pragma unroll
                        for (int j = 0; j < 8; j++) vv[j] = s[(long)j * ksA];
                    }
                } else {
#pragma unroll
                    for (int j = 0; j < 8; j++)
                        vv[j] = Ab[(long)(k0 + kk0 + j) * lda + m0 + mm];
                }
            } else {
#pragma unroll
                for (int j = 0; j < 8; j++) vv[j] = 0.f;
            }
            short8 hi, lo;
#pragma unroll
            for (int j = 0; j < 8; j++) { short h, l; splt(vv[j], h, l); hi[j] = h; lo[j] = l; }
            *(short8*)&As[mm * 40 + kk0] = hi;
            if (PREC == 2) *(short8*)&As[2560 + mm * 40 + kk0] = lo;
        }

        // ---- stage B ----
        if (BMODE == 1) {
            const float4* s4 = (const float4*)((const float*)Bsrc + (long)bz * sB +
                                               (long)(n0 + mm) * ldb + k0 + kk0);
            float4 v0 = s4[0], v1 = s4[1];
            float vv[8] = {v0.x, v0.y, v0.z, v0.w, v1.x, v1.y, v1.z, v1.w};
            short8 hi, lo;
#pragma unroll
            for (int j = 0; j < 8; j++) { short h, l; splt(vv[j], h, l); hi[j] = h; lo[j] = l; }
            *(short8*)&Bs[mm * 40 + kk0] = hi;
            if (PREC == 2) *(short8*)&Bs[2560 + mm * 40 + kk0] = lo;
        } else {
            float vv[8];
            if (BMODE == 0) {
#pragma unroll
                for (int j = 0; j < 8; j++)
                    vv[j] = ((const float*)Bsrc)[(long)bz * sB + (long)(k0 + kk0 + j) * ldb + n0 + mm];
            } else {  // BMODE 3: im2col
                int W = 1 << wsh;
                int n = n0 + mm;
                int hbase = n >> wsh, wbase = n & (W - 1);
#pragma unroll
                for (int j = 0; j < 8; j++) {
                    int kc = k0 + kk0 + j;
                    int c = kc / 9, tap = kc - 9 * c;
                    int h = hbase + tap / 3 - 1, w = wbase + tap % 3 - 1;
                    vv[j] = (h >= 0 && h < H && w >= 0 && w < W)
                          ? ((const float*)Bsrc)[(long)bz * sB + (long)c * ldb + (h << wsh) + w]
                          : 0.f;
                }
            }
            short8 hi, lo;
#pragma unroll
            for (int j = 0; j < 8; j++) { short h, l; splt(vv[j], h, l); hi[j] = h; lo[j] = l; }
            *(short8*)&Bs[mm * 40 + kk0] = hi;
            if (PREC == 2) *(short8*)&Bs[2560 + mm * 40 + kk0] = lo;
        }
        __syncthreads();

        // ---- compute ----
        short8 a0h = *(short8*)&As[(moff + lr) * 40 + lq * 8];
        short8 a1h = *(short8*)&As[(moff + 16 + lr) * 40 + lq * 8];
        short8 b0h = *(short8*)&Bs[(noff + lr) * 40 + lq * 8];
        short8 b1h = *(short8*)&Bs[(noff + 16 + lr) * 40 + lq * 8];
        acc[0][0] = __builtin_amdgcn_mfma_f32_16x16x32_bf16(a0h, b0h, acc[0][0], 0, 0, 0);
        acc[0][1] = __builtin_amdgcn_mfma_f32_16x16x32_bf16(a0h, b1h, acc[0][1], 0, 0, 0);
        acc[1][0] = __builtin_amdgcn_mfma_f32_16x16x32_bf16(a1h, b0h, acc[1][0], 0, 0, 0);
        acc[1][1] = __builtin_amdgcn_mfma_f32_16x16x32_bf16(a1h, b1h, acc[1][1], 0, 0, 0);
        if (PREC == 2) {
            short8 a0l = *(short8*)&As[2560 + (moff + lr) * 40 + lq * 8];
            short8 a1l = *(short8*)&As[2560 + (moff + 16 + lr) * 40 + lq * 8];
            short8 b0l = *(short8*)&Bs[2560 + (noff + lr) * 40 + lq * 8];
            short8 b1l = *(short8*)&Bs[2560 + (noff + 16 + lr) * 40 + lq * 8];
            acc[0][0] = __builtin_amdgcn_mfma_f32_16x16x32_bf16(a0h, b0l, acc[0][0], 0, 0, 0);
            acc[0][1] = __builtin_amdgcn_mfma_f32_16x16x32_bf16(a0h, b1l, acc[0][1], 0, 0, 0);
            acc[1][0] = __builtin_amdgcn_mfma_f32_16x16x32_bf16(a1h, b0l, acc[1][0], 0, 0, 0);
            acc[1][1] = __builtin_amdgcn_mfma_f32_16x16x32_bf16(a1h, b1l, acc[1][1], 0, 0, 0);
            acc[0][0] = __builtin_amdgcn_mfma_f32_16x16x32_bf16(a0l, b0h, acc[0][0], 0, 0, 0);
            acc[0][1] = __builtin_amdgcn_mfma_f32_16x16x32_bf16(a0l, b1h, acc[0][1], 0, 0, 0);
            acc[1][0] = __builtin_amdgcn_mfma_f32_16x16x32_bf16(a1l, b0h, acc[1][0], 0, 0, 0);
            acc[1][1] = __builtin_amdgcn_mfma_f32_16x16x32_bf16(a1l, b1h, acc[1][1], 0, 0, 0);
        }
        __syncthreads();
    }

    // ---- epilogue ----
#pragma unroll
    for (int mi = 0; mi < 2; mi++)
#pragma unroll
        for (int ni = 0; ni < 2; ni++) {
            int col = n0 + noff + ni * 16 + lr;
#pragma unroll
            for (int r = 0; r < 4; r++) {
                int row = m0 + moff + mi * 16 + lq * 4 + r;
                if (row < M) {
                    long o = (long)row * ldc + col;
                    float v = acc[mi][ni][r];
                    if (KSPLIT > 1) {
                        atomicAdd(&Cb[o], v);
                    } else {
                        if (BIAS) v += bias[row];
                        if (ACCUM) v += Cb[o];
                        Cb[o] = v;
                    }
                }
            }
        }
}

// ---------------------------------------------------------------------------
// DCN bilinear corner tables: per (b, tap, p): 4 weights (mask-folded) + addrs
// ---------------------------------------------------------------------------
__global__ void dcnw_k(const float* __restrict__ OO, float4* __restrict__ Tw,
                       int4* __restrict__ Ta, int N, int H, int W)
{
    long idx = (long)blockIdx.x * 256 + threadIdx.x;
    if (idx >= (long)16 * 9 * N) return;
    int b = (int)(idx / (9 * N));
    int r = (int)(idx % (9 * N));
    int tap = r / N, p = r % N;
    int h = p / W, w = p % W;
    const float* oob = OO + (long)b * 27 * N;
    float oy = oob[(2 * tap) * N + p];
    float ox = oob[(2 * tap + 1) * N + p];
    float mz = oob[(18 + tap) * N + p];
    float mask = 1.f / (1.f + expf(-mz));
    float y = (float)(h - 1 + tap / 3) + oy;
    float x = (float)(w - 1 + tap % 3) + ox;
    float y0 = floorf(y), x0 = floorf(x);
    float wy = y - y0, wx = x - x0;
    float ys[2] = {y0, y0 + 1.f};
    float xs[2] = {x0, x0 + 1.f};
    float wys[2] = {1.f - wy, wy};
    float wxs[2] = {1.f - wx, wx};
    float wv[4]; int av[4];
#pragma unroll
    for (int iy = 0; iy < 2; iy++)
#pragma unroll
        for (int ix = 0; ix < 2; ix++) {
            float yy = ys[iy], xx = xs[ix];
            bool valid = (yy >= 0.f) && (yy <= (float)(H - 1)) &&
                         (xx >= 0.f) && (xx <= (float)(W - 1));
            wv[iy * 2 + ix] = valid ? wys[iy] * wxs[ix] * mask : 0.f;
            int yc = (int)fminf(fmaxf(yy, 0.f), (float)(H - 1));
            int xc = (int)fminf(fmaxf(xx, 0.f), (float)(W - 1));
            av[iy * 2 + ix] = yc * W + xc;
        }
    Tw[idx] = (float4){wv[0], wv[1], wv[2], wv[3]};
    Ta[idx] = (int4){av[0], av[1], av[2], av[3]};
}

// DCN weight prepack: Wre[o][tap*256+c] = W[(o*256+c)*9+tap]
__global__ void wre_k(const float* __restrict__ W, float* __restrict__ Wre)
{
    long idx = (long)blockIdx.x * 256 + threadIdx.x;
    if (idx >= 2304L * 256) return;
    int o = (int)(idx / 2304);
    int k = (int)(idx % 2304);
    int tap = k >> 8, c = k & 255;
    Wre[idx] = W[((long)o * 256 + c) * 9 + tap];
}

// ---------------------------------------------------------------------------
// Fused deformable conv: C[b](256 x N) = Wre(256x2304) @ Sampled(2304 x N)
// Sampling on the fly from tables; split hi/lo bf16; all taps in-register.
// grid (N/64, 4*KSPLIT, B).  KSPLIT>1: atomicAdd into bias-prefilled C.
// ---------------------------------------------------------------------------
template <int KSPLIT>
__launch_bounds__(256)
__global__ void dcn_k(const float* __restrict__ Wre, const float4* __restrict__ Tw,
                      const int4* __restrict__ Ta, const float* __restrict__ X,
                      const float* __restrict__ bias, float* __restrict__ C, int N)
{
    __shared__ short As[2 * 2560];
    __shared__ short Bs[2 * 2560];
    const int bz = blockIdx.z;
    const int mt = blockIdx.y / KSPLIT, ch = blockIdx.y % KSPLIT;
    const int m0 = mt * 64, n0 = blockIdx.x * 64;
    const int tid = threadIdx.x;
    const int lane = tid & 63, wv = tid >> 6;
    const int moff = (wv & 1) * 32, noff = (wv >> 1) * 32;
    const int lr = lane & 15, lq = lane >> 4;
    const int mm = tid >> 2, kk0 = (tid & 3) * 8;
    const float* Xb = X + (long)bz * 256 * N;
    float* Cb = C + (long)bz * 256 * N;

    f32x4 acc[2][2];
#pragma unroll
    for (int i = 0; i < 2; i++)
#pragma unroll
        for (int j = 0; j < 2; j++) acc[i][j] = (f32x4){0.f, 0.f, 0.f, 0.f};

    const int itc = 72 / KSPLIT;
    for (int kt = ch * itc; kt < ch * itc + itc; kt++) {
        int tap = kt >> 3, c0 = (kt & 7) * 32;
        // ---- stage A: prepacked weights, contiguous ----
        {
            const float4* s4 = (const float4*)(Wre + (long)(m0 + mm) * 2304 + tap * 256 + c0 + kk0);
            float4 v0 = s4[0], v1 = s4[1];
            float vv[8] = {v0.x, v0.y, v0.z, v0.w, v1.x, v1.y, v1.z, v1.w};
            short8 hi, lo;
#pragma unroll
            for (int j = 0; j < 8; j++) { short h, l; splt(vv[j], h, l); hi[j] = h; lo[j] = l; }
            *(short8*)&As[mm * 40 + kk0] = hi;
            *(short8*)&As[2560 + mm * 40 + kk0] = lo;
        }
        // ---- stage B: sample on the fly ----
        {
            long ti = (long)(bz * 9 + tap) * N + n0 + mm;
            float4 w4 = Tw[ti];
            int4 a4 = Ta[ti];
            short8 hi, lo;
#pragma unroll
            for (int j = 0; j < 8; j++) {
                const float* r = Xb + (long)(c0 + kk0 + j) * N;
                float v = w4.x * r[a4.x] + w4.y * r[a4.y] + w4.z * r[a4.z] + w4.w * r[a4.w];
                short h, l; splt(v, h, l); hi[j] = h; lo[j] = l;
            }
            *(short8*)&Bs[mm * 40 + kk0] = hi;
            *(short8*)&Bs[2560 + mm * 40 + kk0] = lo;
        }
        __syncthreads();

        short8 a0h = *(short8*)&As[(moff + lr) * 40 + lq * 8];
        short8 a1h = *(short8*)&As[(moff + 16 + lr) * 40 + lq * 8];
        short8 b0h = *(short8*)&Bs[(noff + lr) * 40 + lq * 8];
        short8 b1h = *(short8*)&Bs[(noff + 16 + lr) * 40 + lq * 8];
        short8 a0l = *(short8*)&As[2560 + (moff + lr) * 40 + lq * 8];
        short8 a1l = *(short8*)&As[2560 + (moff + 16 + lr) * 40 + lq * 8];
        short8 b0l = *(short8*)&Bs[2560 + (noff + lr) * 40 + lq * 8];
        short8 b1l = *(short8*)&Bs[2560 + (noff + 16 + lr) * 40 + lq * 8];
        acc[0][0] = __builtin_amdgcn_mfma_f32_16x16x32_bf16(a0h, b0h, acc[0][0], 0, 0, 0);
        acc[0][1] = __builtin_amdgcn_mfma_f32_16x16x32_bf16(a0h, b1h, acc[0][1], 0, 0, 0);
        acc[1][0] = __builtin_amdgcn_mfma_f32_16x16x32_bf16(a1h, b0h, acc[1][0], 0, 0, 0);
        acc[1][1] = __builtin_amdgcn_mfma_f32_16x16x32_bf16(a1h, b1h, acc[1][1], 0, 0, 0);
        acc[0][0] = __builtin_amdgcn_mfma_f32_16x16x32_bf16(a0h, b0l, acc[0][0], 0, 0, 0);
        acc[0][1] = __builtin_amdgcn_mfma_f32_16x16x32_bf16(a0h, b1l, acc[0][1], 0, 0, 0);
        acc[1][0] = __builtin_amdgcn_mfma_f32_16x16x32_bf16(a1h, b0l, acc[1][0], 0, 0, 0);
        acc[1][1] = __builtin_amdgcn_mfma_f32_16x16x32_bf16(a1h, b1l, acc[1][1], 0, 0, 0);
        acc[0][0] = __builtin_amdgcn_mfma_f32_16x16x32_bf16(a0l, b0h, acc[0][0], 0, 0, 0);
        acc[0][1] = __builtin_amdgcn_mfma_f32_16x16x32_bf16(a0l, b1h, acc[0][1], 0, 0, 0);
        acc[1][0] = __builtin_amdgcn_mfma_f32_16x16x32_bf16(a1l, b0h, acc[1][0], 0, 0, 0);
        acc[1][1] = __builtin_amdgcn_mfma_f32_16x16x32_bf16(a1l, b1h, acc[1][1], 0, 0, 0);
        __syncthreads();
    }

#pragma unroll
    for (int mi = 0; mi < 2; mi++)
#pragma unroll
        for (int ni = 0; ni < 2; ni++) {
            int col = n0 + noff + ni * 16 + lr;
#pragma unroll
            for (int r = 0; r < 4; r++) {
                int row = m0 + moff + mi * 16 + lq * 4 + r;
                long o = (long)row * N + col;
                if (KSPLIT > 1) atomicAdd(&Cb[o], acc[mi][ni][r]);
                else            Cb[o] = acc[mi][ni][r] + bias[row];
            }
        }
}

// Softmax over batch axis (16)
__global__ void softmax_b_k(float* __restrict__ att, long NN)
{
    long idx = (long)blockIdx.x * 256 + threadIdx.x;
    if (idx >= NN) return;
    float r[16];
    float mx = -1e30f;
#pragma unroll
    for (int b = 0; b < 16; b++) {
        r[b] = att[(long)b * NN + idx];
        mx = fmaxf(mx, r[b]);
    }
    float s = 0.f;
#pragma unroll
    for (int b = 0; b < 16; b++) { r[b] = expf(r[b] - mx); s += r[b]; }
    float inv = 1.f / s;
#pragma unroll
    for (int b = 0; b < 16; b++) att[(long)b * NN + idx] = r[b] * inv;
}

// M[b][c][d] = softmax_c(gram_t) + softmax_c(gram_s)
__global__ void gram_sm_k(const float* __restrict__ gt, const float* __restrict__ gs,
                          float* __restrict__ Mo)
{
    int b = blockIdx.x;
    int d = blockIdx.y * 64 + threadIdx.x;
    const float* gtb = gt + (long)b * 65536;
    const float* gsb = gs + (long)b * 65536;
    float* mb = Mo + (long)b * 65536;
    float mt = -1e30f, ms = -1e30f;
    for (int c = 0; c < 256; c++) {
        mt = fmaxf(mt, gtb[c * 256 + d]);
        ms = fmaxf(ms, gsb[c * 256 + d]);
    }
    float st = 0.f, ss = 0.f;
    for (int c = 0; c < 256; c++) {
        st += expf(gtb[c * 256 + d] - mt);
        ss += expf(gsb[c * 256 + d] - ms);
    }
    float it = 1.f / st, is = 1.f / ss;
    for (int c = 0; c < 256; c++)
        mb[c * 256 + d] = expf(gtb[c * 256 + d] - mt) * it +
                          expf(gsb[c * 256 + d] - ms) * is;
}

__global__ void cast_out_k(const float* __restrict__ t, const float* __restrict__ s,
                           void* __restrict__ out, long nt, long ntot,
                           const int* __restrict__ flag)
{
    long idx = (long)blockIdx.x * 256 + threadIdx.x;
    if (idx >= ntot) return;
    float v = (idx < nt) ? t[idx] : s[idx - nt];
    if (*flag) ((float*)out)[idx] = v;
    else       ((bf16*)out)[idx] = __float2bfloat16(v);
}

// ---------------------------------------------------------------------------
extern "C" void kernel_launch(void* const* d_in, const int* in_sizes, int n_in,
                              void* d_out, int out_size, void* d_ws, size_t ws_size,
                              hipStream_t stream)
{
    const int B = 16, C = 256;
    const int Nt = 256, Ns = 1024;
    const long sXt = (long)C * Nt, sXs = (long)C * Ns;
    dim3 blk(256);

    float* ws = (float*)d_ws;
    int* flag = (int*)d_ws;
    long off = 16;
    auto alloc = [&](long n) { float* p = ws + off; off += n; return p; };

    float* xt32     = alloc((long)B * C * Nt);
    float* xs32     = alloc((long)B * C * Ns);   // -> out_s_f32 (dead after gram-s)
    float* Wf       = alloc(1470464);
    float* q_t      = alloc((long)B * 32 * Nt);
    float* k_t      = alloc((long)B * 32 * Nt);
    float* v_t      = alloc((long)B * C * Nt);
    float* q_s      = alloc((long)B * 32 * Ns);
    float* k_s      = alloc((long)B * 32 * Ns);
    float* v_s      = alloc((long)B * C * Ns);   // -> DCN prep region
    float* gram_t   = alloc((long)B * C * C);    // -> out_t_f32
    float* gram_s   = alloc((long)B * C * C);
    float* Mc       = alloc((long)B * C * C);
    float* att_t    = alloc((long)B * Nt * Nt);  // xtT early / attT_t late
    float* att_slab = alloc((long)B * Ns * 256); // xsT early / attT_slab late
    float* at       = alloc((long)B * C * Nt);
    float* asr      = alloc((long)B * C * Ns);
    float* oo_t     = alloc((long)B * 27 * Nt);
    float* oo_s     = alloc((long)B * 27 * Ns);

    float* out_t_f32 = gram_t;
    float* out_s_f32 = xs32;
    float* xtT       = att_t;       // dead before attT_t is written
    float* xsT       = att_slab;    // dead before attT_slab is written
    // DCN prep region inside v_s (v_s dead after slab applies): 2.66M < 4.19M
    float* Wre_t = v_s;
    float* Wre_s = v_s + 589824;
    float4* Tw_t = (float4*)(v_s + 2 * 589824);
    int4*   Ta_t = (int4*)(v_s + 2 * 589824 + 147456);
    float4* Tw_s = (float4*)(v_s + 2 * 589824 + 2 * 147456);
    int4*   Ta_s = (int4*)(v_s + 2 * 589824 + 2 * 147456 + 589824);

    // ---- 0) detect + ingest ----
    detect_k<<<dim3(1), blk, 0, stream>>>((const unsigned short*)d_in[0], flag);
    long woff[22];
    {
        long acc = 0;
        for (int i = 2; i < 22; i++) { woff[i] = acc; acc += (in_sizes[i] + 7) & ~7L; }
    }
    IArgs ia;
    long tot = 0;
    auto seg = [&](int s, const void* src, float* dst, long n) {
        ia.src[s] = src; ia.dst[s] = dst; ia.start[s] = tot; tot += n;
    };
    seg(0, d_in[0], xt32, (long)B * C * Nt);
    seg(1, d_in[0], at,   (long)B * C * Nt);
    seg(2, d_in[1], xs32, (long)B * C * Ns);
    seg(3, d_in[1], asr,  (long)B * C * Ns);
    for (int i = 2; i < 22; i++) seg(2 + i, d_in[i], Wf + woff[i], in_sizes[i]);
    ia.start[NSEG] = tot;
    ingest_all_k<<<dim3((unsigned)((tot + 255) / 256)), blk, 0, stream>>>(ia, flag);

    const float *tq_w = Wf + woff[2],  *tq_b = Wf + woff[3];
    const float *tk_w = Wf + woff[4],  *tk_b = Wf + woff[5];
    const float *tv_w = Wf + woff[6],  *tv_b = Wf + woff[7];
    const float *sq_w = Wf + woff[8],  *sq_b = Wf + woff[9];
    const float *sk_w = Wf + woff[10], *sk_b = Wf + woff[11];
    const float *sv_w = Wf + woff[12], *sv_b = Wf + woff[13];
    const float *t_off_w = Wf + woff[14], *t_off_b = Wf + woff[15];
    const float *t_dcn_w = Wf + woff[16], *t_dcn_b = Wf + woff[17];
    const float *s_off_w = Wf + woff[18], *s_off_b = Wf + woff[19];
    const float *s_dcn_w = Wf + woff[20], *s_dcn_b = Wf + woff[21];

    // ---- 1) transposes + prefills ----
    tr_k<<<dim3(Nt / 32, 8, B), dim3(32, 8), 0, stream>>>(xt32, xtT, Nt);
    tr_k<<<dim3(Ns / 32, 8, B), dim3(32, 8), 0, stream>>>(xs32, xsT, Ns);
    fill_k<<<dim3((2 * B * C * C) / 256), blk, 0, stream>>>(gram_t, nullptr, 1, 1, 2L * B * C * C);
    fill_k<<<dim3((B * 27 * Nt + 255) / 256), blk, 0, stream>>>(oo_t, t_off_b, 27L * Nt, Nt, (long)B * 27 * Nt);
    fill_k<<<dim3((B * 27 * Ns + 255) / 256), blk, 0, stream>>>(oo_s, s_off_b, 27L * Ns, Ns, (long)B * 27 * Ns);

    // ---- 2) q,k,v projections (B = x^T, BMODE1, PREC2) ----
    mgemm<false, 1, false, true, 2, 1><<<dim3(Nt / 64, 1, B), blk, 0, stream>>>(
        tq_w, 256, 1, 0, xtT, 256, sXt, q_t, Nt, (long)32 * Nt, tq_b, 32, Nt, 256, 0, 0);
    mgemm<false, 1, false, true, 2, 1><<<dim3(Nt / 64, 1, B), blk, 0, stream>>>(
        tk_w, 256, 1, 0, xtT, 256, sXt, k_t, Nt, (long)32 * Nt, tk_b, 32, Nt, 256, 0, 0);
    mgemm<false, 1, false, true, 2, 1><<<dim3(Nt / 64, 4, B), blk, 0, stream>>>(
        tv_w, 256, 1, 0, xtT, 256, sXt, v_t, Nt, sXt, tv_b, 256, Nt, 256, 0, 0);
    mgemm<false, 1, false, true, 2, 1><<<dim3(Ns / 64, 1, B), blk, 0, stream>>>(
        sq_w, 256, 1, 0, xsT, 256, sXs, q_s, Ns, (long)32 * Ns, sq_b, 32, Ns, 256, 0, 0);
    mgemm<false, 1, false, true, 2, 1><<<dim3(Ns / 64, 1, B), blk, 0, stream>>>(
        sk_w, 256, 1, 0, xsT, 256, sXs, k_s, Ns, (long)32 * Ns, sk_b, 32, Ns, 256, 0, 0);
    mgemm<false, 1, false, true, 2, 1><<<dim3(Ns / 64, 4, B), blk, 0, stream>>>(
        sv_w, 256, 1, 0, xsT, 256, sXs, v_s, Ns, sXs, sv_b, 256, Ns, 256, 0, 0);

    // ---- 3) gram matrices (BMODE1, K-split 4) ----
    mgemm<false, 1, false, false, 1, 4><<<dim3(4, 16, B), blk, 0, stream>>>(
        xt32, Nt, 1, sXt, xt32, Nt, sXt, gram_t, 256, (long)C * C, nullptr, 256, 256, Nt, 0, 0);
    mgemm<false, 1, false, false, 1, 4><<<dim3(4, 16, B), blk, 0, stream>>>(
        xs32, Ns, 1, sXs, xs32, Ns, sXs, gram_s, 256, (long)C * C, nullptr, 256, 256, Ns, 0, 0);

    // ---- 4) M ----
    gram_sm_k<<<dim3(B, 4), dim3(64), 0, stream>>>(gram_t, gram_s, Mc);

    // ---- 5) channel attention (B = x^T, BMODE1) ----
    mgemm<false, 1, true, false, 2, 2><<<dim3(Nt / 64, 8, B), blk, 0, stream>>>(
        Mc, 256, 1, (long)C * C, xtT, 256, sXt, at, Nt, sXt, nullptr, 256, Nt, 256, 0, 0);
    mgemm<false, 1, true, false, 2, 1><<<dim3(Ns / 64, 4, B), blk, 0, stream>>>(
        Mc, 256, 1, (long)C * C, xsT, 256, sXs, asr, Ns, sXs, nullptr, 256, Ns, 256, 0, 0);

    // ---- 6) template spatial attention (logits transposed: attT[m][n]) ----
    mgemm<true, 0, false, false, 2, 1><<<dim3(4, 4, B), blk, 0, stream>>>(
        k_t, Nt, 1, (long)32 * Nt, q_t, Nt, (long)32 * Nt, att_t, Nt, (long)Nt * Nt,
        nullptr, Nt, Nt, 32, 0, 0);
    softmax_b_k<<<dim3((Nt * Nt) / 256), blk, 0, stream>>>(att_t, (long)Nt * Nt);
    mgemm<false, 1, true, false, 2, 2><<<dim3(Nt / 64, 8, B), blk, 0, stream>>>(
        v_t, Nt, 1, sXt, att_t, Nt, (long)Nt * Nt, at, Nt, sXt, nullptr, 256, Nt, Nt, 0, 0);

    // ---- 7) search spatial attention, 4 m-slabs (transposed logits) ----
    for (int m0s = 0; m0s < Ns; m0s += 256) {
        mgemm<true, 0, false, false, 2, 1><<<dim3(Ns / 64, 4, B), blk, 0, stream>>>(
            k_s + m0s, Ns, 1, (long)32 * Ns, q_s, Ns, (long)32 * Ns,
            att_slab, Ns, (long)256 * Ns, nullptr, 256, Ns, 32, 0, 0);
        softmax_b_k<<<dim3((256 * Ns) / 256), blk, 0, stream>>>(att_slab, (long)256 * Ns);
        mgemm<false, 1, true, false, 2, 4><<<dim3(4, 16, B), blk, 0, stream>>>(
            v_s, Ns, 1, sXs, att_slab, Ns, (long)256 * Ns,
            asr + m0s, Ns, sXs, nullptr, 256, 256, Ns, 0, 0);
    }

    // ---- 8) offset convs (im2col, K-split 4, bias prefilled) ----
    mgemm<false, 3, false, false, 2, 4><<<dim3(Nt / 64, 4, B), blk, 0, stream>>>(
        t_off_w, 2304, 1, 0, at, Nt, sXt, oo_t, Nt, (long)27 * Nt,
        nullptr, 27, Nt, 2304, 16, 4);
    mgemm<false, 3, false, false, 2, 4><<<dim3(Ns / 64, 4, B), blk, 0, stream>>>(
        s_off_w, 2304, 1, 0, asr, Ns, sXs, oo_s, Ns, (long)27 * Ns,
        nullptr, 27, Ns, 2304, 32, 5);

    // ---- 9) DCN prep (v_s region now dead) ----
    wre_k<<<dim3((2304 * 256) / 256), blk, 0, stream>>>(t_dcn_w, Wre_t);
    wre_k<<<dim3((2304 * 256) / 256), blk, 0, stream>>>(s_dcn_w, Wre_s);
    dcnw_k<<<dim3((B * 9 * Nt) / 256), blk, 0, stream>>>(oo_t, Tw_t, Ta_t, Nt, 16, 16);
    dcnw_k<<<dim3((B * 9 * Ns) / 256), blk, 0, stream>>>(oo_s, Tw_s, Ta_s, Ns, 32, 32);

    // ---- 10) fused deformable convs ----
    fill_k<<<dim3((B * C * Nt + 255) / 256), blk, 0, stream>>>(
        out_t_f32, t_dcn_b, (long)C * Nt, Nt, (long)B * C * Nt);
    dcn_k<2><<<dim3(Nt / 64, 8, B), blk, 0, stream>>>(
        Wre_t, Tw_t, Ta_t, at, t_dcn_b, out_t_f32, Nt);
    dcn_k<1><<<dim3(Ns / 64, 4, B), blk, 0, stream>>>(
        Wre_s, Tw_s, Ta_s, asr, s_dcn_b, out_s_f32, Ns);

    // ---- 11) emit output ----
    long nt = (long)B * C * Nt;
    long ntot = nt + (long)B * C * Ns;
    cast_out_k<<<dim3((unsigned)((ntot + 255) / 256)), blk, 0, stream>>>(
        out_t_f32, out_s_f32, d_out, nt, ntot, flag);
}

// Round 8
// 1317.894 us; speedup vs baseline: 2.3283x; 1.1380x over previous
//
#include <hip/hip_runtime.h>
#include <hip/hip_bf16.h>

typedef __hip_bfloat16 bf16;
typedef __attribute__((ext_vector_type(8))) short short8;
typedef __attribute__((ext_vector_type(4))) float f32x4;

__device__ __forceinline__ short f2b(float v)
{
    union { bf16 b; short s; } u;
    u.b = __float2bfloat16(v);
    return u.s;
}
__device__ __forceinline__ float b2f(short s)
{
    union { short s; bf16 b; } u;
    u.s = s;
    return __bfloat162float(u.b);
}
__device__ __forceinline__ void splt(float v, short& hi, short& lo)
{
    hi = f2b(v);
    lo = f2b(v - b2f(hi));
}
// Bs column swizzle: logical k-group g at LDS row r -> phys slot ((g + r>>3)&3).
// Breaks the pitch-40 Δrow=8 bank aliasing for lane-per-row b128 writes (≤2-way).
__device__ __forceinline__ int bsw(int row, int g)
{
    return row * 40 + (((g + (row >> 3)) & 3) << 3);
}

// ---------------------------------------------------------------------------
// Dtype detector (validated r2): flag=1 -> fp32 storage, 0 -> bf16.
// ---------------------------------------------------------------------------
__global__ void detect_k(const unsigned short* __restrict__ p, int* __restrict__ flag)
{
    __shared__ int cnt;
    if (threadIdx.x == 0) cnt = 0;
    __syncthreads();
    int bad = 0;
    for (int i = threadIdx.x; i < 4096; i += 256) {
        unsigned short u = p[2 * i];
        int e = (u >> 7) & 0xFF;
        if (e != 0 && (e < 100 || e > 140)) bad++;
    }
    atomicAdd(&cnt, bad);
    __syncthreads();
    if (threadIdx.x == 0) *flag = (cnt > 1024) ? 1 : 0;
}

// ---------------------------------------------------------------------------
// Fused ingest (validated r5)
// ---------------------------------------------------------------------------
#define NSEG 24
struct IArgs {
    const void* src[NSEG];
    float* dst[NSEG];
    long start[NSEG + 1];
};

__global__ void ingest_all_k(IArgs a, const int* __restrict__ flag)
{
    long i = (long)blockIdx.x * 256 + threadIdx.x;
    if (i >= a.start[NSEG]) return;
    int s = 0;
#pragma unroll
    for (int j = 1; j < NSEG; j++) s += (i >= a.start[j]) ? 1 : 0;
    long idx = i - a.start[s];
    float v;
    if (*flag) v = ((const float*)a.src[s])[idx];
    else       v = __bfloat162float(((const bf16*)a.src[s])[idx]);
    a.dst[s][idx] = v;
}

// C[b][m][n] = bias[m] (or 0).  total = B*MN.
__global__ void fill_k(float* __restrict__ C, const float* __restrict__ bias,
                       long MN, int Nn, long total)
{
    long i = (long)blockIdx.x * 256 + threadIdx.x;
    if (i >= total) return;
    float v = 0.f;
    if (bias) {
        long r = i % MN;
        v = bias[(int)(r / Nn)];
    }
    C[i] = v;
}

// Tiled transpose: X[b][c][n] -> XT[b][n][c].  C=256. grid (N/32, 8, B), blk (32,8)
__global__ void tr_k(const float* __restrict__ X, float* __restrict__ XT, int N)
{
    __shared__ float t[32][33];
    int b = blockIdx.z, n0 = blockIdx.x * 32, c0 = blockIdx.y * 32;
    const float* Xb = X + (long)b * 256 * N;
    float* Tb = XT + (long)b * 256 * N;
    int tx = threadIdx.x, ty = threadIdx.y;
#pragma unroll
    for (int i = 0; i < 4; i++)
        t[ty + 8 * i][tx] = Xb[(long)(c0 + ty + 8 * i) * N + n0 + tx];
    __syncthreads();
#pragma unroll
    for (int i = 0; i < 4; i++)
        Tb[(long)(n0 + ty + 8 * i) * 256 + c0 + tx] = t[tx][ty + 8 * i];
}

// ---------------------------------------------------------------------------
// MFMA bf16 GEMM.
//   0: B[k*ldb+n]  — lane=n mapping (coalesced), swizzled Bs
//   1: B[n*ldb+k]  — float4 per-thread, swizzled Bs
//   3: im2col (3x3 SAME) — lane=n mapping, swizzled Bs
// PREC2 = split hi/lo (3 MFMA).  KSPLIT>1: atomicAdd into pre-initialized C.
// ---------------------------------------------------------------------------
template <bool TRA, int BMODE, bool ACCUM, bool BIAS, int PREC, int KSPLIT>
__launch_bounds__(256)
__global__ void mgemm(const float* __restrict__ A, int lda, int ksA, long sA,
                      const void* __restrict__ Bsrc, int ldb, long sB,
                      float* __restrict__ C, int ldc, long sC,
                      const float* __restrict__ bias,
                      int M, int N, int K, int H, int wsh)
{
    __shared__ short As[PREC * 2560];
    __shared__ short Bs[PREC * 2560];

    const int bz = blockIdx.z;
    const float* Ab = A + (long)bz * sA;
    float* Cb = C + (long)bz * sC;
    const int mt = blockIdx.y / KSPLIT, ch = blockIdx.y % KSPLIT;
    const int m0 = mt * 64, n0 = blockIdx.x * 64;
    const int kchunk = K / KSPLIT;
    const int kbeg = ch * kchunk, kend = kbeg + kchunk;
    const int tid = threadIdx.x;

    f32x4 acc[2][2];
#pragma unroll
    for (int i = 0; i < 2; i++)
#pragma unroll
        for (int j = 0; j < 2; j++) acc[i][j] = (f32x4){0.f, 0.f, 0.f, 0.f};

    const int lane = tid & 63, wv = tid >> 6;
    const int moff = (wv & 1) * 32, noff = (wv >> 1) * 32;
    const int lr = lane & 15, lq = lane >> 4;
    const int mm = tid >> 2, kk0 = (tid & 3) * 8;   // A / BMODE1 map
    const int nn = tid & 63, kg = tid >> 6;         // BMODE0/3 map

    for (int k0 = kbeg; k0 < kend; k0 += 32) {
        // ---- stage A (m-major, contiguous) ----
        {
            float vv[8];
            if (m0 + mm < M) {
                if (!TRA) {
                    if (ksA == 1) {
                        const float4* s4 = (const float4*)(Ab + (long)(m0 + mm) * lda + k0 + kk0);
                        float4 v0 = s4[0], v1 = s4[1];
                        vv[0] = v0.x; vv[1] = v0.y; vv[2] = v0.z; vv[3] = v0.w;
                        vv[4] = v1.x; vv[5] = v1.y; vv[6] = v1.z; vv[7] = v1.w;
                    } else {
                        const float* s = Ab + (long)(m0 + mm) * lda + (long)(k0 + kk0) * ksA;
#pragma unroll
                        for (int j = 0; j < 8; j++) vv[j] = s[(long)j * ksA];
                    }
                } else {
#pragma unroll
                    for (int j = 0; j < 8; j++)
                        vv[j] = Ab[(long)(k0 + kk0 + j) * lda + m0 + mm];
                }
            } else {
#pragma unroll
                for (int j = 0; j < 8; j++) vv[j] = 0.f;
            }
            short8 hi, lo;
#pragma unroll
            for (int j = 0; j < 8; j++) { short h, l; splt(vv[j], h, l); hi[j] = h; lo[j] = l; }
            *(short8*)&As[mm * 40 + kk0] = hi;
            if (PREC == 2) *(short8*)&As[2560 + mm * 40 + kk0] = lo;
        }

        // ---- stage B (swizzled Bs) ----
        if (BMODE == 1) {
            const float4* s4 = (const float4*)((const float*)Bsrc + (long)bz * sB +
                                               (long)(n0 + mm) * ldb + k0 + kk0);
            float4 v0 = s4[0], v1 = s4[1];
            float vv[8] = {v0.x, v0.y, v0.z, v0.w, v1.x, v1.y, v1.z, v1.w};
            short8 hi, lo;
#pragma unroll
            for (int j = 0; j < 8; j++) { short h, l; splt(vv[j], h, l); hi[j] = h; lo[j] = l; }
            int o = bsw(mm, tid & 3);
            *(short8*)&Bs[o] = hi;
            if (PREC == 2) *(short8*)&Bs[2560 + o] = lo;
        } else {
            // lane = n (coalesced across lanes), 8 k-consecutive per thread
            float vv[8];
            if (BMODE == 0) {
#pragma unroll
                for (int j = 0; j < 8; j++)
                    vv[j] = ((const float*)Bsrc)[(long)bz * sB + (long)(k0 + kg * 8 + j) * ldb + n0 + nn];
            } else {  // BMODE 3: im2col
                int W = 1 << wsh;
                int n = n0 + nn;
                int hbase = n >> wsh, wbase = n & (W - 1);
#pragma unroll
                for (int j = 0; j < 8; j++) {
                    int kc = k0 + kg * 8 + j;
                    int c = kc / 9, tap = kc - 9 * c;
                    int h = hbase + tap / 3 - 1, w = wbase + tap % 3 - 1;
                    vv[j] = (h >= 0 && h < H && w >= 0 && w < W)
                          ? ((const float*)Bsrc)[(long)bz * sB + (long)c * ldb + (h << wsh) + w]
                          : 0.f;
                }
            }
            short8 hi, lo;
#pragma unroll
            for (int j = 0; j < 8; j++) { short h, l; splt(vv[j], h, l); hi[j] = h; lo[j] = l; }
            int o = bsw(nn, kg);
            *(short8*)&Bs[o] = hi;
            if (PREC == 2) *(short8*)&Bs[2560 + o] = lo;
        }
        __syncthreads();

        // ---- compute ----
        int rb0 = noff + lr, rb1 = noff + 16 + lr;
        short8 a0h = *(short8*)&As[(moff + lr) * 40 + lq * 8];
        short8 a1h = *(short8*)&As[(moff + 16 + lr) * 40 + lq * 8];
        short8 b0h = *(short8*)&Bs[bsw(rb0, lq)];
        short8 b1h = *(short8*)&Bs[bsw(rb1, lq)];
        acc[0][0] = __builtin_amdgcn_mfma_f32_16x16x32_bf16(a0h, b0h, acc[0][0], 0, 0, 0);
        acc[0][1] = __builtin_amdgcn_mfma_f32_16x16x32_bf16(a0h, b1h, acc[0][1], 0, 0, 0);
        acc[1][0] = __builtin_amdgcn_mfma_f32_16x16x32_bf16(a1h, b0h, acc[1][0], 0, 0, 0);
        acc[1][1] = __builtin_amdgcn_mfma_f32_16x16x32_bf16(a1h, b1h, acc[1][1], 0, 0, 0);
        if (PREC == 2) {
            short8 a0l = *(short8*)&As[2560 + (moff + lr) * 40 + lq * 8];
            short8 a1l = *(short8*)&As[2560 + (moff + 16 + lr) * 40 + lq * 8];
            short8 b0l = *(short8*)&Bs[2560 + bsw(rb0, lq)];
            short8 b1l = *(short8*)&Bs[2560 + bsw(rb1, lq)];
            acc[0][0] = __builtin_amdgcn_mfma_f32_16x16x32_bf16(a0h, b0l, acc[0][0], 0, 0, 0);
            acc[0][1] = __builtin_amdgcn_mfma_f32_16x16x32_bf16(a0h, b1l, acc[0][1], 0, 0, 0);
            acc[1][0] = __builtin_amdgcn_mfma_f32_16x16x32_bf16(a1h, b0l, acc[1][0], 0, 0, 0);
            acc[1][1] = __builtin_amdgcn_mfma_f32_16x16x32_bf16(a1h, b1l, acc[1][1], 0, 0, 0);
            acc[0][0] = __builtin_amdgcn_mfma_f32_16x16x32_bf16(a0l, b0h, acc[0][0], 0, 0, 0);
            acc[0][1] = __builtin_amdgcn_mfma_f32_16x16x32_bf16(a0l, b1h, acc[0][1], 0, 0, 0);
            acc[1][0] = __builtin_amdgcn_mfma_f32_16x16x32_bf16(a1l, b0h, acc[1][0], 0, 0, 0);
            acc[1][1] = __builtin_amdgcn_mfma_f32_16x16x32_bf16(a1l, b1h, acc[1][1], 0, 0, 0);
        }
        __syncthreads();
    }

    // ---- epilogue ----
#pragma unroll
    for (int mi = 0; mi < 2; mi++)
#pragma unroll
        for (int ni = 0; ni < 2; ni++) {
            int col = n0 + noff + ni * 16 + lr;
#pragma unroll
            for (int r = 0; r < 4; r++) {
                int row = m0 + moff + mi * 16 + lq * 4 + r;
                if (row < M) {
                    long o = (long)row * ldc + col;
                    float v = acc[mi][ni][r];
                    if (KSPLIT > 1) {
                        atomicAdd(&Cb[o], v);
                    } else {
                        if (BIAS) v += bias[row];
                        if (ACCUM) v += Cb[o];
                        Cb[o] = v;
                    }
                }
            }
        }
}

// ---------------------------------------------------------------------------
// DCN bilinear corner tables
// ---------------------------------------------------------------------------
__global__ void dcnw_k(const float* __restrict__ OO, float4* __restrict__ Tw,
                       int4* __restrict__ Ta, int N, int H, int W)
{
    long idx = (long)blockIdx.x * 256 + threadIdx.x;
    if (idx >= (long)16 * 9 * N) return;
    int b = (int)(idx / (9 * N));
    int r = (int)(idx % (9 * N));
    int tap = r / N, p = r % N;
    int h = p / W, w = p % W;
    const float* oob = OO + (long)b * 27 * N;
    float oy = oob[(2 * tap) * N + p];
    float ox = oob[(2 * tap + 1) * N + p];
    float mz = oob[(18 + tap) * N + p];
    float mask = 1.f / (1.f + expf(-mz));
    float y = (float)(h - 1 + tap / 3) + oy;
    float x = (float)(w - 1 + tap % 3) + ox;
    float y0 = floorf(y), x0 = floorf(x);
    float wy = y - y0, wx = x - x0;
    float ys[2] = {y0, y0 + 1.f};
    float xs[2] = {x0, x0 + 1.f};
    float wys[2] = {1.f - wy, wy};
    float wxs[2] = {1.f - wx, wx};
    float wv[4]; int av[4];
#pragma unroll
    for (int iy = 0; iy < 2; iy++)
#pragma unroll
        for (int ix = 0; ix < 2; ix++) {
            float yy = ys[iy], xx = xs[ix];
            bool valid = (yy >= 0.f) && (yy <= (float)(H - 1)) &&
                         (xx >= 0.f) && (xx <= (float)(W - 1));
            wv[iy * 2 + ix] = valid ? wys[iy] * wxs[ix] * mask : 0.f;
            int yc = (int)fminf(fmaxf(yy, 0.f), (float)(H - 1));
            int xc = (int)fminf(fmaxf(xx, 0.f), (float)(W - 1));
            av[iy * 2 + ix] = yc * W + xc;
        }
    Tw[idx] = (float4){wv[0], wv[1], wv[2], wv[3]};
    Ta[idx] = (int4){av[0], av[1], av[2], av[3]};
}

// DCN weight prepack: Wre[o][tap*256+c] = W[(o*256+c)*9+tap]
__global__ void wre_k(const float* __restrict__ W, float* __restrict__ Wre)
{
    long idx = (long)blockIdx.x * 256 + threadIdx.x;
    if (idx >= 2304L * 256) return;
    int o = (int)(idx / 2304);
    int k = (int)(idx % 2304);
    int tap = k >> 8, c = k & 255;
    Wre[idx] = W[((long)o * 256 + c) * 9 + tap];
}

// ---------------------------------------------------------------------------
// Fused deformable conv, lane = position mapping for sampling (coalesced).
// grid (N/64, 4*KSPLIT, B).  KSPLIT>1: atomicAdd into bias-prefilled C.
// ---------------------------------------------------------------------------
template <int KSPLIT>
__launch_bounds__(256)
__global__ void dcn_k(const float* __restrict__ Wre, const float4* __restrict__ Tw,
                      const int4* __restrict__ Ta, const float* __restrict__ X,
                      const float* __restrict__ bias, float* __restrict__ C, int N)
{
    __shared__ short As[2 * 2560];
    __shared__ short Bs[2 * 2560];
    const int bz = blockIdx.z;
    const int mt = blockIdx.y / KSPLIT, ch = blockIdx.y % KSPLIT;
    const int m0 = mt * 64, n0 = blockIdx.x * 64;
    const int tid = threadIdx.x;
    const int lane = tid & 63, wv = tid >> 6;
    const int moff = (wv & 1) * 32, noff = (wv >> 1) * 32;
    const int lr = lane & 15, lq = lane >> 4;
    const int mm = tid >> 2, kk0 = (tid & 3) * 8;   // A map
    const int nn = tid & 63, kg = tid >> 6;         // B map (lane = position)
    const float* Xb = X + (long)bz * 256 * N;
    float* Cb = C + (long)bz * 256 * N;

    f32x4 acc[2][2];
#pragma unroll
    for (int i = 0; i < 2; i++)
#pragma unroll
        for (int j = 0; j < 2; j++) acc[i][j] = (f32x4){0.f, 0.f, 0.f, 0.f};

    const int itc = 72 / KSPLIT;
    for (int kt = ch * itc; kt < ch * itc + itc; kt++) {
        int tap = kt >> 3, c0 = (kt & 7) * 32;
        // ---- stage A: prepacked weights, contiguous ----
        {
            const float4* s4 = (const float4*)(Wre + (long)(m0 + mm) * 2304 + tap * 256 + c0 + kk0);
            float4 v0 = s4[0], v1 = s4[1];
            float vv[8] = {v0.x, v0.y, v0.z, v0.w, v1.x, v1.y, v1.z, v1.w};
            short8 hi, lo;
#pragma unroll
            for (int j = 0; j < 8; j++) { short h, l; splt(vv[j], h, l); hi[j] = h; lo[j] = l; }
            *(short8*)&As[mm * 40 + kk0] = hi;
            *(short8*)&As[2560 + mm * 40 + kk0] = lo;
        }
        // ---- stage B: sample on the fly, lane = position ----
        {
            long ti = (long)(bz * 9 + tap) * N + n0 + nn;
            float4 w4 = Tw[ti];
            int4 a4 = Ta[ti];
            short8 hi, lo;
#pragma unroll
            for (int j = 0; j < 8; j++) {
                const float* r = Xb + (long)(c0 + kg * 8 + j) * N;
                float v = w4.x * r[a4.x] + w4.y * r[a4.y] + w4.z * r[a4.z] + w4.w * r[a4.w];
                short h, l; splt(v, h, l); hi[j] = h; lo[j] = l;
            }
            int o = bsw(nn, kg);
            *(short8*)&Bs[o] = hi;
            *(short8*)&Bs[2560 + o] = lo;
        }
        __syncthreads();

        int rb0 = noff + lr, rb1 = noff + 16 + lr;
        short8 a0h = *(short8*)&As[(moff + lr) * 40 + lq * 8];
        short8 a1h = *(short8*)&As[(moff + 16 + lr) * 40 + lq * 8];
        short8 b0h = *(short8*)&Bs[bsw(rb0, lq)];
        short8 b1h = *(short8*)&Bs[bsw(rb1, lq)];
        short8 a0l = *(short8*)&As[2560 + (moff + lr) * 40 + lq * 8];
        short8 a1l = *(short8*)&As[2560 + (moff + 16 + lr) * 40 + lq * 8];
        short8 b0l = *(short8*)&Bs[2560 + bsw(rb0, lq)];
        short8 b1l = *(short8*)&Bs[2560 + bsw(rb1, lq)];
        acc[0][0] = __builtin_amdgcn_mfma_f32_16x16x32_bf16(a0h, b0h, acc[0][0], 0, 0, 0);
        acc[0][1] = __builtin_amdgcn_mfma_f32_16x16x32_bf16(a0h, b1h, acc[0][1], 0, 0, 0);
        acc[1][0] = __builtin_amdgcn_mfma_f32_16x16x32_bf16(a1h, b0h, acc[1][0], 0, 0, 0);
        acc[1][1] = __builtin_amdgcn_mfma_f32_16x16x32_bf16(a1h, b1h, acc[1][1], 0, 0, 0);
        acc[0][0] = __builtin_amdgcn_mfma_f32_16x16x32_bf16(a0h, b0l, acc[0][0], 0, 0, 0);
        acc[0][1] = __builtin_amdgcn_mfma_f32_16x16x32_bf16(a0h, b1l, acc[0][1], 0, 0, 0);
        acc[1][0] = __builtin_amdgcn_mfma_f32_16x16x32_bf16(a1h, b0l, acc[1][0], 0, 0, 0);
        acc[1][1] = __builtin_amdgcn_mfma_f32_16x16x32_bf16(a1h, b1l, acc[1][1], 0, 0, 0);
        acc[0][0] = __builtin_amdgcn_mfma_f32_16x16x32_bf16(a0l, b0h, acc[0][0], 0, 0, 0);
        acc[0][1] = __builtin_amdgcn_mfma_f32_16x16x32_bf16(a0l, b1h, acc[0][1], 0, 0, 0);
        acc[1][0] = __builtin_amdgcn_mfma_f32_16x16x32_bf16(a1l, b0h, acc[1][0], 0, 0, 0);
        acc[1][1] = __builtin_amdgcn_mfma_f32_16x16x32_bf16(a1l, b1h, acc[1][1], 0, 0, 0);
        __syncthreads();
    }

#pragma unroll
    for (int mi = 0; mi < 2; mi++)
#pragma unroll
        for (int ni = 0; ni < 2; ni++) {
            int col = n0 + noff + ni * 16 + lr;
#pragma unroll
            for (int r = 0; r < 4; r++) {
                int row = m0 + moff + mi * 16 + lq * 4 + r;
                long o = (long)row * N + col;
                if (KSPLIT > 1) atomicAdd(&Cb[o], acc[mi][ni][r]);
                else            Cb[o] = acc[mi][ni][r] + bias[row];
            }
        }
}

// Softmax over batch axis (16)
__global__ void softmax_b_k(float* __restrict__ att, long NN)
{
    long idx = (long)blockIdx.x * 256 + threadIdx.x;
    if (idx >= NN) return;
    float r[16];
    float mx = -1e30f;
#pragma unroll
    for (int b = 0; b < 16; b++) {
        r[b] = att[(long)b * NN + idx];
        mx = fmaxf(mx, r[b]);
    }
    float s = 0.f;
#pragma unroll
    for (int b = 0; b < 16; b++) { r[b] = expf(r[b] - mx); s += r[b]; }
    float inv = 1.f / s;
#pragma unroll
    for (int b = 0; b < 16; b++) att[(long)b * NN + idx] = r[b] * inv;
}

// M[b][c][d] = softmax_c(gram_t) + softmax_c(gram_s)
__global__ void gram_sm_k(const float* __restrict__ gt, const float* __restrict__ gs,
                          float* __restrict__ Mo)
{
    int b = blockIdx.x;
    int d = blockIdx.y * 64 + threadIdx.x;
    const float* gtb = gt + (long)b * 65536;
    const float* gsb = gs + (long)b * 65536;
    float* mb = Mo + (long)b * 65536;
    float mt = -1e30f, ms = -1e30f;
    for (int c = 0; c < 256; c++) {
        mt = fmaxf(mt, gtb[c * 256 + d]);
        ms = fmaxf(ms, gsb[c * 256 + d]);
    }
    float st = 0.f, ss = 0.f;
    for (int c = 0; c < 256; c++) {
        st += expf(gtb[c * 256 + d] - mt);
        ss += expf(gsb[c * 256 + d] - ms);
    }
    float it = 1.f / st, is = 1.f / ss;
    for (int c = 0; c < 256; c++)
        mb[c * 256 + d] = expf(gtb[c * 256 + d] - mt) * it +
                          expf(gsb[c * 256 + d] - ms) * is;
}

__global__ void cast_out_k(const float* __restrict__ t, const float* __restrict__ s,
                           void* __restrict__ out, long nt, long ntot,
                           const int* __restrict__ flag)
{
    long idx = (long)blockIdx.x * 256 + threadIdx.x;
    if (idx >= ntot) return;
    float v = (idx < nt) ? t[idx] : s[idx - nt];
    if (*flag) ((float*)out)[idx] = v;
    else       ((bf16*)out)[idx] = __float2bfloat16(v);
}

// ---------------------------------------------------------------------------
extern "C" void kernel_launch(void* const* d_in, const int* in_sizes, int n_in,
                              void* d_out, int out_size, void* d_ws, size_t ws_size,
                              hipStream_t stream)
{
    const int B = 16, C = 256;
    const int Nt = 256, Ns = 1024;
    const long sXt = (long)C * Nt, sXs = (long)C * Ns;
    dim3 blk(256);

    float* ws = (float*)d_ws;
    int* flag = (int*)d_ws;
    long off = 16;
    auto alloc = [&](long n) { float* p = ws + off; off += n; return p; };

    float* xt32     = alloc((long)B * C * Nt);
    float* xs32     = alloc((long)B * C * Ns);   // -> out_s_f32
    float* Wf       = alloc(1470464);
    float* q_t      = alloc((long)B * 32 * Nt);
    float* k_t      = alloc((long)B * 32 * Nt);
    float* v_t      = alloc((long)B * C * Nt);
    float* q_s      = alloc((long)B * 32 * Ns);
    float* k_s      = alloc((long)B * 32 * Ns);
    float* v_s      = alloc((long)B * C * Ns);   // -> DCN prep region
    float* gram_t   = alloc((long)B * C * C);    // -> out_t_f32
    float* gram_s   = alloc((long)B * C * C);
    float* Mc       = alloc((long)B * C * C);
    float* att_t    = alloc((long)B * Nt * Nt);  // xtT early / attT_t late
    float* att_slab = alloc((long)B * Ns * 256); // xsT early / attT_slab late
    float* at       = alloc((long)B * C * Nt);
    float* asr      = alloc((long)B * C * Ns);
    float* oo_t     = alloc((long)B * 27 * Nt);
    float* oo_s     = alloc((long)B * 27 * Ns);

    float* out_t_f32 = gram_t;
    float* out_s_f32 = xs32;
    float* xtT       = att_t;
    float* xsT       = att_slab;
    float* Wre_t = v_s;
    float* Wre_s = v_s + 589824;
    float4* Tw_t = (float4*)(v_s + 2 * 589824);
    int4*   Ta_t = (int4*)(v_s + 2 * 589824 + 147456);
    float4* Tw_s = (float4*)(v_s + 2 * 589824 + 2 * 147456);
    int4*   Ta_s = (int4*)(v_s + 2 * 589824 + 2 * 147456 + 589824);

    // ---- 0) detect + ingest ----
    detect_k<<<dim3(1), blk, 0, stream>>>((const unsigned short*)d_in[0], flag);
    long woff[22];
    {
        long acc = 0;
        for (int i = 2; i < 22; i++) { woff[i] = acc; acc += (in_sizes[i] + 7) & ~7L; }
    }
    IArgs ia;
    long tot = 0;
    auto seg = [&](int s, const void* src, float* dst, long n) {
        ia.src[s] = src; ia.dst[s] = dst; ia.start[s] = tot; tot += n;
    };
    seg(0, d_in[0], xt32, (long)B * C * Nt);
    seg(1, d_in[0], at,   (long)B * C * Nt);
    seg(2, d_in[1], xs32, (long)B * C * Ns);
    seg(3, d_in[1], asr,  (long)B * C * Ns);
    for (int i = 2; i < 22; i++) seg(2 + i, d_in[i], Wf + woff[i], in_sizes[i]);
    ia.start[NSEG] = tot;
    ingest_all_k<<<dim3((unsigned)((tot + 255) / 256)), blk, 0, stream>>>(ia, flag);

    const float *tq_w = Wf + woff[2],  *tq_b = Wf + woff[3];
    const float *tk_w = Wf + woff[4],  *tk_b = Wf + woff[5];
    const float *tv_w = Wf + woff[6],  *tv_b = Wf + woff[7];
    const float *sq_w = Wf + woff[8],  *sq_b = Wf + woff[9];
    const float *sk_w = Wf + woff[10], *sk_b = Wf + woff[11];
    const float *sv_w = Wf + woff[12], *sv_b = Wf + woff[13];
    const float *t_off_w = Wf + woff[14], *t_off_b = Wf + woff[15];
    const float *t_dcn_w = Wf + woff[16], *t_dcn_b = Wf + woff[17];
    const float *s_off_w = Wf + woff[18], *s_off_b = Wf + woff[19];
    const float *s_dcn_w = Wf + woff[20], *s_dcn_b = Wf + woff[21];

    // ---- 1) transposes + prefills ----
    tr_k<<<dim3(Nt / 32, 8, B), dim3(32, 8), 0, stream>>>(xt32, xtT, Nt);
    tr_k<<<dim3(Ns / 32, 8, B), dim3(32, 8), 0, stream>>>(xs32, xsT, Ns);
    fill_k<<<dim3((2 * B * C * C) / 256), blk, 0, stream>>>(gram_t, nullptr, 1, 1, 2L * B * C * C);
    fill_k<<<dim3((B * 27 * Nt + 255) / 256), blk, 0, stream>>>(oo_t, t_off_b, 27L * Nt, Nt, (long)B * 27 * Nt);
    fill_k<<<dim3((B * 27 * Ns + 255) / 256), blk, 0, stream>>>(oo_s, s_off_b, 27L * Ns, Ns, (long)B * 27 * Ns);

    // ---- 2) q,k,v projections (B = x^T, BMODE1, PREC2) ----
    mgemm<false, 1, false, true, 2, 1><<<dim3(Nt / 64, 1, B), blk, 0, stream>>>(
        tq_w, 256, 1, 0, xtT, 256, sXt, q_t, Nt, (long)32 * Nt, tq_b, 32, Nt, 256, 0, 0);
    mgemm<false, 1, false, true, 2, 1><<<dim3(Nt / 64, 1, B), blk, 0, stream>>>(
        tk_w, 256, 1, 0, xtT, 256, sXt, k_t, Nt, (long)32 * Nt, tk_b, 32, Nt, 256, 0, 0);
    mgemm<false, 1, false, true, 2, 1><<<dim3(Nt / 64, 4, B), blk, 0, stream>>>(
        tv_w, 256, 1, 0, xtT, 256, sXt, v_t, Nt, sXt, tv_b, 256, Nt, 256, 0, 0);
    mgemm<false, 1, false, true, 2, 1><<<dim3(Ns / 64, 1, B), blk, 0, stream>>>(
        sq_w, 256, 1, 0, xsT, 256, sXs, q_s, Ns, (long)32 * Ns, sq_b, 32, Ns, 256, 0, 0);
    mgemm<false, 1, false, true, 2, 1><<<dim3(Ns / 64, 1, B), blk, 0, stream>>>(
        sk_w, 256, 1, 0, xsT, 256, sXs, k_s, Ns, (long)32 * Ns, sk_b, 32, Ns, 256, 0, 0);
    mgemm<false, 1, false, true, 2, 1><<<dim3(Ns / 64, 4, B), blk, 0, stream>>>(
        sv_w, 256, 1, 0, xsT, 256, sXs, v_s, Ns, sXs, sv_b, 256, Ns, 256, 0, 0);

    // ---- 3) gram matrices (BMODE1, K-split 4) ----
    mgemm<false, 1, false, false, 1, 4><<<dim3(4, 16, B), blk, 0, stream>>>(
        xt32, Nt, 1, sXt, xt32, Nt, sXt, gram_t, 256, (long)C * C, nullptr, 256, 256, Nt, 0, 0);
    mgemm<false, 1, false, false, 1, 4><<<dim3(4, 16, B), blk, 0, stream>>>(
        xs32, Ns, 1, sXs, xs32, Ns, sXs, gram_s, 256, (long)C * C, nullptr, 256, 256, Ns, 0, 0);

    // ---- 4) M ----
    gram_sm_k<<<dim3(B, 4), dim3(64), 0, stream>>>(gram_t, gram_s, Mc);

    // ---- 5) channel attention (B = x^T, BMODE1) ----
    mgemm<false, 1, true, false, 2, 2><<<dim3(Nt / 64, 8, B), blk, 0, stream>>>(
        Mc, 256, 1, (long)C * C, xtT, 256, sXt, at, Nt, sXt, nullptr, 256, Nt, 256, 0, 0);
    mgemm<false, 1, true, false, 2, 1><<<dim3(Ns / 64, 4, B), blk, 0, stream>>>(
        Mc, 256, 1, (long)C * C, xsT, 256, sXs, asr, Ns, sXs, nullptr, 256, Ns, 256, 0, 0);

    // ---- 6) template spatial attention (logits transposed: attT[m][n]) ----
    mgemm<true, 0, false, false, 2, 1><<<dim3(4, 4, B), blk, 0, stream>>>(
        k_t, Nt, 1, (long)32 * Nt, q_t, Nt, (long)32 * Nt, att_t, Nt, (long)Nt * Nt,
        nullptr, Nt, Nt, 32, 0, 0);
    softmax_b_k<<<dim3((Nt * Nt) / 256), blk, 0, stream>>>(att_t, (long)Nt * Nt);
    mgemm<false, 1, true, false, 2, 2><<<dim3(Nt / 64, 8, B), blk, 0, stream>>>(
        v_t, Nt, 1, sXt, att_t, Nt, (long)Nt * Nt, at, Nt, sXt, nullptr, 256, Nt, Nt, 0, 0);

    // ---- 7) search spatial attention, 4 m-slabs (transposed logits) ----
    for (int m0s = 0; m0s < Ns; m0s += 256) {
        mgemm<true, 0, false, false, 2, 1><<<dim3(Ns / 64, 4, B), blk, 0, stream>>>(
            k_s + m0s, Ns, 1, (long)32 * Ns, q_s, Ns, (long)32 * Ns,
            att_slab, Ns, (long)256 * Ns, nullptr, 256, Ns, 32, 0, 0);
        softmax_b_k<<<dim3((256 * Ns) / 256), blk, 0, stream>>>(att_slab, (long)256 * Ns);
        mgemm<false, 1, true, false, 2, 4><<<dim3(4, 16, B), blk, 0, stream>>>(
            v_s, Ns, 1, sXs, att_slab, Ns, (long)256 * Ns,
            asr + m0s, Ns, sXs, nullptr, 256, 256, Ns, 0, 0);
    }

    // ---- 8) offset convs (im2col, K-split 4, bias prefilled) ----
    mgemm<false, 3, false, false, 2, 4><<<dim3(Nt / 64, 4, B), blk, 0, stream>>>(
        t_off_w, 2304, 1, 0, at, Nt, sXt, oo_t, Nt, (long)27 * Nt,
        nullptr, 27, Nt, 2304, 16, 4);
    mgemm<false, 3, false, false, 2, 4><<<dim3(Ns / 64, 4, B), blk, 0, stream>>>(
        s_off_w, 2304, 1, 0, asr, Ns, sXs, oo_s, Ns, (long)27 * Ns,
        nullptr, 27, Ns, 2304, 32, 5);

    // ---- 9) DCN prep ----
    wre_k<<<dim3((2304 * 256) / 256), blk, 0, stream>>>(t_dcn_w, Wre_t);
    wre_k<<<dim3((2304 * 256) / 256), blk, 0, stream>>>(s_dcn_w, Wre_s);
    dcnw_k<<<dim3((B * 9 * Nt) / 256), blk, 0, stream>>>(oo_t, Tw_t, Ta_t, Nt, 16, 16);
    dcnw_k<<<dim3((B * 9 * Ns) / 256), blk, 0, stream>>>(oo_s, Tw_s, Ta_s, Ns, 32, 32);

    // ---- 10) fused deformable convs ----
    fill_k<<<dim3((B * C * Nt + 255) / 256), blk, 0, stream>>>(
        out_t_f32, t_dcn_b, (long)C * Nt, Nt, (long)B * C * Nt);
    dcn_k<2><<<dim3(Nt / 64, 8, B), blk, 0, stream>>>(
        Wre_t, Tw_t, Ta_t, at, t_dcn_b, out_t_f32, Nt);
    dcn_k<1><<<dim3(Ns / 64, 4, B), blk, 0, stream>>>(
        Wre_s, Tw_s, Ta_s, asr, s_dcn_b, out_s_f32, Ns);

    // ---- 11) emit output ----
    long nt = (long)B * C * Nt;
    long ntot = nt + (long)B * C * Ns;
    cast_out_k<<<dim3((unsigned)((ntot + 255) / 256)), blk, 0, stream>>>(
        out_t_f32, out_s_f32, d_out, nt, ntot, flag);
}